// Round 6
// baseline (904.922 us; speedup 1.0000x reference)
//
#include <hip/hip_runtime.h>
#include <stdint.h>
#include <stddef.h>

#define BB 256
#define DD 512
#define PP 5
#define NCLS 11003
#define SEGC 6
#define SCALEF 28.0f
#define ALPHAF 0.6f
#define BETAF 0.4f
#define SPF 10.0f
#define SNF 40.0f

__device__ __forceinline__ float waveSum(float v) {
#pragma unroll
    for (int o = 32; o; o >>= 1) v += __shfl_down(v, o);
    return v;
}

__device__ __forceinline__ float softplusf(float x) {
    return fmaxf(x, 0.f) + log1pf(__expf(-fabsf(x)));
}

// ---------------- dtype detection / conversion ----------------
// labels may be int32 or int64; vmask/tmask may be bool(1B) or int32.
__global__ __launch_bounds__(256) void convert_k(const void* labels_raw,
                                                 const void* vm_raw,
                                                 const void* tm_raw,
                                                 int* __restrict__ labs,
                                                 unsigned char* __restrict__ vmb,
                                                 unsigned char* __restrict__ tmb) {
    __shared__ int is64, v32, t32;
    if (threadIdx.x == 0) {
        const int* L = (const int*)labels_raw;
        int f = 1;
        for (int j = 0; j < 16; j++) if (L[2 * j + 1] != 0) f = 0;
        is64 = f;
        const int* V = (const int*)vm_raw;
        f = 1;
        for (int j = 0; j < 16; j++) if ((unsigned)V[j] > 1u) f = 0;
        v32 = f;
        const int* T = (const int*)tm_raw;
        f = 1;
        for (int j = 0; j < 16; j++) if ((unsigned)T[j] > 1u) f = 0;
        t32 = f;
    }
    __syncthreads();
    int i = threadIdx.x;
    if (i < BB) {
        if (is64) labs[i] = (int)((const long long*)labels_raw)[i];
        else      labs[i] = ((const int*)labels_raw)[i];
    }
    for (int j = i; j < BB * PP; j += 256) {
        vmb[j] = v32 ? (unsigned char)(((const int*)vm_raw)[j] != 0)
                     : (unsigned char)(((const unsigned char*)vm_raw)[j] != 0);
        tmb[j] = t32 ? (unsigned char)(((const int*)tm_raw)[j] != 0)
                     : (unsigned char)(((const unsigned char*)tm_raw)[j] != 0);
    }
}

// ---------------- row L2-normalize (rows of length 512) ----------------
__global__ __launch_bounds__(256) void norm_rows_k(const float* __restrict__ src,
                                                   float* __restrict__ dst) {
    int row = blockIdx.x;
    const float* s = src + (size_t)row * DD;
    float v0 = s[threadIdx.x];
    float v1 = s[threadIdx.x + 256];
    float ss = v0 * v0 + v1 * v1;
    __shared__ float red[4];
    __shared__ float inv;
    float v = waveSum(ss);
    if ((threadIdx.x & 63) == 0) red[threadIdx.x >> 6] = v;
    __syncthreads();
    if (threadIdx.x == 0) inv = 1.0f / sqrtf(red[0] + red[1] + red[2] + red[3]);
    __syncthreads();
    float* d = dst + (size_t)row * DD;
    d[threadIdx.x] = v0 * inv;
    d[threadIdx.x + 256] = v1 * inv;
}

// ---------------- W column inverse-norm * SCALE ----------------
__global__ __launch_bounds__(256) void wnorm_k(const float* __restrict__ W,
                                               float* __restrict__ swn) {
    int c = blockIdx.x * 256 + threadIdx.x;
    if (c >= NCLS) return;
    float ss = 0.f;
    for (int k = 0; k < DD; k++) {
        float w = W[(size_t)k * NCLS + c];
        ss = fmaf(w, w, ss);
    }
    swn[c] = SCALEF / sqrtf(ss);
}

// ---------------- instance loss: GEMM (512 x NCLS, K=512) + sumexp ----------------
// Xn = [vn; tn] (512 rows). logit = (Xn . Wcol) * swn[c];  sumexp[row] += exp(logit)
__global__ __launch_bounds__(256) void inst_gemm_k(const float* __restrict__ Xn,
                                                   const float* __restrict__ W,
                                                   const float* __restrict__ swn,
                                                   float* __restrict__ sumexp) {
    int c = blockIdx.x * 256 + threadIdx.x;
    int row0 = blockIdx.y * 32;
    bool valid = c < NCLS;
    int cc = valid ? c : NCLS - 1;
    float acc[32];
#pragma unroll
    for (int m = 0; m < 32; m++) acc[m] = 0.f;
    for (int k = 0; k < DD; k += 4) {
        float w0 = W[(size_t)(k + 0) * NCLS + cc];
        float w1 = W[(size_t)(k + 1) * NCLS + cc];
        float w2 = W[(size_t)(k + 2) * NCLS + cc];
        float w3 = W[(size_t)(k + 3) * NCLS + cc];
        const float* xp = Xn + (size_t)row0 * DD + k;
#pragma unroll
        for (int m = 0; m < 32; m++) {
            const float* xr = xp + (size_t)m * DD;
            float a = acc[m];
            a = fmaf(xr[0], w0, a);
            a = fmaf(xr[1], w1, a);
            a = fmaf(xr[2], w2, a);
            a = fmaf(xr[3], w3, a);
            acc[m] = a;
        }
    }
    float sc = swn[cc];
#pragma unroll
    for (int m = 0; m < 32; m++) {
        float e = valid ? __expf(acc[m] * sc) : 0.f;
        e = waveSum(e);
        if ((threadIdx.x & 63) == 0) atomicAdd(&sumexp[row0 + m], e);
    }
}

__global__ __launch_bounds__(256) void inst_final_k(const float* __restrict__ Xn,
                                                    const float* __restrict__ W,
                                                    const float* __restrict__ swn,
                                                    const float* __restrict__ sumexp,
                                                    const int* __restrict__ labs,
                                                    float* __restrict__ out) {
    int i = threadIdx.x;  // 256 threads
    int lab = labs[i];
    float dv = 0.f, dt = 0.f;
    for (int k = 0; k < DD; k++) {
        float w = W[(size_t)k * NCLS + lab];
        dv = fmaf(Xn[(size_t)i * DD + k], w, dv);
        dt = fmaf(Xn[(size_t)(BB + i) * DD + k], w, dt);
    }
    float s = swn[lab];
    float li = (logf(sumexp[i]) - dv * s) + (logf(sumexp[BB + i]) - dt * s);
    __shared__ float red[4];
    float v = waveSum(li);
    if ((i & 63) == 0) red[i >> 6] = v;
    __syncthreads();
    if (i == 0) out[0] = (red[0] + red[1] + red[2] + red[3]) * (1.0f / BB);
}

// ---------------- mask loss ----------------
__global__ __launch_bounds__(256) void mask_loss_k(const float* __restrict__ seg,
                                                   const int* __restrict__ masks,
                                                   double* __restrict__ acc) {
    int idx = blockIdx.x * 256 + threadIdx.x;  // < 5,242,880
    int n = idx >> 12;
    int pix = idx & 4095;
    const float* p = seg + (size_t)n * SEGC * 4096 + pix;
    float x0 = p[0], x1 = p[4096], x2 = p[8192];
    float x3 = p[12288], x4 = p[16384], x5 = p[20480];
    float mx = fmaxf(fmaxf(fmaxf(x0, x1), fmaxf(x2, x3)), fmaxf(x4, x5));
    float se = __expf(x0 - mx) + __expf(x1 - mx) + __expf(x2 - mx) +
               __expf(x3 - mx) + __expf(x4 - mx) + __expf(x5 - mx);
    int m = masks[idx];
    float xm = (m == 0) ? x0 : (m == 1) ? x1 : (m == 2) ? x2
             : (m == 3) ? x3 : (m == 4) ? x4 : x5;
    float ce = logf(se) + mx - xm;
    __shared__ float red[4];
    float v = waveSum(ce);
    if ((threadIdx.x & 63) == 0) red[threadIdx.x >> 6] = v;
    __syncthreads();
    if (threadIdx.x == 0)
        atomicAdd(&acc[blockIdx.x & 63], (double)(red[0] + red[1] + red[2] + red[3]));
}

// ---------------- sim matrices: z=0 -> vn@tn^T ; z=1..5 -> pn[z-1]@an[z-1]^T ----------------
__global__ __launch_bounds__(256) void sim_k(const float* __restrict__ vn,
                                             const float* __restrict__ tn,
                                             const float* __restrict__ pn,
                                             const float* __restrict__ an,
                                             float* __restrict__ sims) {
    int z = blockIdx.z;
    const float* X;
    const float* Y;
    if (z == 0) { X = vn; Y = tn; }
    else { X = pn + (size_t)(z - 1) * BB * DD; Y = an + (size_t)(z - 1) * BB * DD; }
    float* C = sims + (size_t)z * BB * BB;
    int row0 = blockIdx.y * 32, col0 = blockIdx.x * 32;
    int tx = threadIdx.x & 15, ty = threadIdx.x >> 4;
    __shared__ float Xs[32][33], Ys[32][33];
    float a00 = 0, a01 = 0, a10 = 0, a11 = 0;
    for (int kc = 0; kc < DD; kc += 32) {
#pragma unroll
        for (int l = 0; l < 4; l++) {
            int idx = threadIdx.x + l * 256;
            int r = idx >> 5, kk = idx & 31;
            Xs[r][kk] = X[(size_t)(row0 + r) * DD + kc + kk];
            Ys[r][kk] = Y[(size_t)(col0 + r) * DD + kc + kk];
        }
        __syncthreads();
#pragma unroll
        for (int kk = 0; kk < 32; kk++) {
            float x0 = Xs[ty * 2][kk], x1 = Xs[ty * 2 + 1][kk];
            float y0 = Ys[tx * 2][kk], y1 = Ys[tx * 2 + 1][kk];
            a00 = fmaf(x0, y0, a00);
            a01 = fmaf(x0, y1, a01);
            a10 = fmaf(x1, y0, a10);
            a11 = fmaf(x1, y1, a11);
        }
        __syncthreads();
    }
    int r = row0 + ty * 2, c = col0 + tx * 2;
    C[(size_t)r * BB + c] = a00;
    C[(size_t)r * BB + c + 1] = a01;
    C[(size_t)(r + 1) * BB + c] = a10;
    C[(size_t)(r + 1) * BB + c + 1] = a11;
}

// ---------------- top-8 boost flags per part ----------------
__global__ __launch_bounds__(256) void boost_k(const float* __restrict__ sims,
                                               unsigned char* __restrict__ b1,
                                               unsigned char* __restrict__ b2) {
    int i = blockIdx.x;  // part index
    const float* S = sims + (size_t)(i + 1) * BB * BB;
    int c = threadIdx.x;
    __shared__ float rowv[BB], colv[BB];
    rowv[c] = S[(size_t)i * BB + c];
    colv[c] = S[(size_t)c * BB + i];
    __syncthreads();
    float rv = rowv[c], cv = colv[c];
    int rank1 = 0, rank2 = 0;
    for (int j = 0; j < BB; j++) {
        rank1 += rowv[j] > rv;
        rank2 += colv[j] > cv;
    }
    unsigned char bo1 = 0, bo2 = 0;
    if (rank1 < 8) {  // c in fwd1: is row i among top-8 of column c?
        int cnt = 0;
        for (int a = 0; a < BB; a++) cnt += S[(size_t)a * BB + c] > rv;
        bo1 = (cnt < 8);
    }
    if (rank2 < 8) {  // c in fwd2: is column i among top-8 of row c?
        int cnt = 0;
        for (int b = 0; b < BB; b++) cnt += S[(size_t)c * BB + b] > cv;
        bo2 = (cnt < 8);
    }
    b1[i * BB + c] = bo1;
    b2[i * BB + c] = bo2;
}

// ---------------- global align ----------------
__global__ __launch_bounds__(256) void galign_k(const float* __restrict__ sim,
                                                const int* __restrict__ labs,
                                                double* __restrict__ acc) {
    int r = blockIdx.x, c = threadIdx.x;
    float s = sim[(size_t)r * BB + c];
    float x = (labs[r] == labs[c]) ? (-SPF * (s - ALPHAF)) : (SNF * (s - BETAF));
    float v = softplusf(x);
    __shared__ float red[4];
    v = waveSum(v);
    if ((threadIdx.x & 63) == 0) red[threadIdx.x >> 6] = v;
    __syncthreads();
    if (threadIdx.x == 0)
        atomicAdd(&acc[blockIdx.x & 7], (double)(red[0] + red[1] + red[2] + red[3]));
}

// ---------------- local align (b1 + b2 terms fused) ----------------
__global__ __launch_bounds__(256) void lalign_k(const float* __restrict__ sims,
                                                const int* __restrict__ labs,
                                                const unsigned char* __restrict__ vmb,
                                                const unsigned char* __restrict__ tmb,
                                                const unsigned char* __restrict__ b1,
                                                const unsigned char* __restrict__ b2,
                                                double* __restrict__ acc) {
    int i = blockIdx.y, r = blockIdx.x, c = threadIdx.x;
    const float* S = sims + (size_t)(i + 1) * BB * BB;
    float s = S[(size_t)r * BB + c];
    bool m = labs[r] == labs[c];
    float Lp = softplusf(-SPF * (s - ALPHAF));
    float Ln = softplusf(SNF * (s - BETAF));
    bool pmr = vmb[r * PP + i] != 0;
    bool pmc = vmb[c * PP + i] != 0;
    bool amc = tmb[c * PP + i] != 0;
    float v = 0.f;
    // b1 term: weight pm[r] & am[c]; pos = match | boost1[c]
    if (pmr && amc) v += (m || (b1[i * BB + c] != 0)) ? Lp : Ln;
    // b2 term (transposed, re-indexed): weight (pm[c]&am[c]) & pm[r]; pos = match | boost2[r]
    if (pmc && amc && pmr) v += (m || (b2[i * BB + r] != 0)) ? Lp : Ln;
    __shared__ float red[4];
    v = waveSum(v);
    if ((threadIdx.x & 63) == 0) red[threadIdx.x >> 6] = v;
    __syncthreads();
    if (threadIdx.x == 0)
        atomicAdd(&acc[blockIdx.x & 7], (double)(red[0] + red[1] + red[2] + red[3]));
}

// ---------------- finalize ----------------
// accs layout: [0..63] mask slots, [64..71] global slots, [72..79] local slots
__global__ void finalize_k(const double* __restrict__ accs, float* __restrict__ out) {
    int t = threadIdx.x;  // 64 threads
    double mv = accs[t];
    double gv = (t < 8) ? accs[64 + t] : 0.0;
    double lv = (t < 8) ? accs[72 + t] : 0.0;
#pragma unroll
    for (int o = 32; o; o >>= 1) {
        mv += __shfl_down(mv, o);
        gv += __shfl_down(gv, o);
        lv += __shfl_down(lv, o);
    }
    if (t == 0) {
        out[1] = (float)((double)PP * mv / 5242880.0);
        out[2] = (float)(2.0 * gv / (double)BB);
        out[3] = (float)(lv / (double)(BB * PP));
    }
}

extern "C" void kernel_launch(void* const* d_in, const int* in_sizes, int n_in,
                              void* d_out, int out_size, void* d_ws, size_t ws_size,
                              hipStream_t stream) {
    const float* visual  = (const float*)d_in[0];
    const float* textual = (const float*)d_in[1];
    const float* part    = (const float*)d_in[2];
    const float* attr    = (const float*)d_in[3];
    const float* seg     = (const float*)d_in[4];
    const float* W       = (const float*)d_in[5];
    const void*  labels  = d_in[6];
    const int*   masks   = (const int*)d_in[7];
    const void*  vmask   = d_in[8];
    const void*  tmask   = d_in[9];
    float* out = (float*)d_out;

    float* ws = (float*)d_ws;
    float* vn  = ws;                       // 256*512
    float* tn  = vn + BB * DD;             // 256*512 (contiguous with vn => Xn)
    float* pn  = tn + BB * DD;             // 5*256*512
    float* an  = pn + PP * BB * DD;        // 5*256*512
    float* swn = an + PP * BB * DD;        // 11008
    float* sims = swn + 11008;             // 6*65536
    float* sumexp = sims + 6 * BB * BB;    // 512
    int* labs = (int*)(sumexp + 2 * BB);   // 256 ints
    unsigned char* vmb = (unsigned char*)(labs + BB);  // 1280
    unsigned char* tmb = vmb + BB * PP;                // 1280
    unsigned char* b1  = tmb + BB * PP;                // 1280
    unsigned char* b2  = b1 + BB * PP;                 // 1280
    uintptr_t aaddr = ((uintptr_t)(b2 + BB * PP) + 15) & ~(uintptr_t)15;
    double* accs = (double*)aaddr;                     // 80 doubles

    hipMemsetAsync(sumexp, 0, 2 * BB * sizeof(float), stream);
    hipMemsetAsync(accs, 0, 80 * sizeof(double), stream);

    convert_k<<<1, 256, 0, stream>>>(labels, vmask, tmask, labs, vmb, tmb);

    norm_rows_k<<<BB, 256, 0, stream>>>(visual, vn);
    norm_rows_k<<<BB, 256, 0, stream>>>(textual, tn);
    norm_rows_k<<<PP * BB, 256, 0, stream>>>(part, pn);
    norm_rows_k<<<PP * BB, 256, 0, stream>>>(attr, an);

    wnorm_k<<<(NCLS + 255) / 256, 256, 0, stream>>>(W, swn);

    dim3 gg((NCLS + 255) / 256, 16);
    inst_gemm_k<<<gg, 256, 0, stream>>>(vn, W, swn, sumexp);
    inst_final_k<<<1, 256, 0, stream>>>(vn, W, swn, sumexp, labs, out);

    mask_loss_k<<<5242880 / 256, 256, 0, stream>>>(seg, masks, accs);

    dim3 sg(8, 8, 6);
    sim_k<<<sg, 256, 0, stream>>>(vn, tn, pn, an, sims);
    boost_k<<<PP, 256, 0, stream>>>(sims, b1, b2);

    galign_k<<<BB, 256, 0, stream>>>(sims, labs, accs + 64);
    dim3 lg(BB, PP);
    lalign_k<<<lg, 256, 0, stream>>>(sims, labs, vmb, tmb, b1, b2, accs + 72);

    finalize_k<<<1, 64, 0, stream>>>(accs, out);
}

// Round 7
// 426.048 us; speedup vs baseline: 2.1240x; 2.1240x over previous
//
#include <hip/hip_runtime.h>
#include <stdint.h>
#include <stddef.h>

#define BB 256
#define DD 512
#define PP 5
#define NCLS 11003
#define NCP 11008   // padded to 172*64
#define SEGC 6
#define SCALEF 28.0f
#define ALPHAF 0.6f
#define BETAF 0.4f
#define SPF 10.0f
#define SNF 40.0f

typedef __attribute__((ext_vector_type(8))) short bf16x8;
typedef __attribute__((ext_vector_type(4))) float f32x4;

__device__ __forceinline__ float waveSum(float v) {
#pragma unroll
    for (int o = 32; o; o >>= 1) v += __shfl_down(v, o);
    return v;
}

__device__ __forceinline__ float softplusf(float x) {
    return fmaxf(x, 0.f) + log1pf(__expf(-fabsf(x)));
}

__device__ __forceinline__ short to_bf16(float f) {
    uint32_t u = __float_as_uint(f);
    uint32_t r = (u + 0x7FFFu + ((u >> 16) & 1u)) >> 16;
    return (short)r;
}

// ---------------- dtype detection / conversion ----------------
__global__ __launch_bounds__(256) void convert_k(const void* labels_raw,
                                                 const void* vm_raw,
                                                 const void* tm_raw,
                                                 int* __restrict__ labs,
                                                 unsigned char* __restrict__ vmb,
                                                 unsigned char* __restrict__ tmb) {
    __shared__ int is64, v32, t32;
    if (threadIdx.x == 0) {
        const int* L = (const int*)labels_raw;
        int f = 1;
        for (int j = 0; j < 16; j++) if (L[2 * j + 1] != 0) f = 0;
        is64 = f;
        const int* V = (const int*)vm_raw;
        f = 1;
        for (int j = 0; j < 16; j++) if ((unsigned)V[j] > 1u) f = 0;
        v32 = f;
        const int* T = (const int*)tm_raw;
        f = 1;
        for (int j = 0; j < 16; j++) if ((unsigned)T[j] > 1u) f = 0;
        t32 = f;
    }
    __syncthreads();
    int i = threadIdx.x;
    if (i < BB) {
        if (is64) labs[i] = (int)((const long long*)labels_raw)[i];
        else      labs[i] = ((const int*)labels_raw)[i];
    }
    for (int j = i; j < BB * PP; j += 256) {
        vmb[j] = v32 ? (unsigned char)(((const int*)vm_raw)[j] != 0)
                     : (unsigned char)(((const unsigned char*)vm_raw)[j] != 0);
        tmb[j] = t32 ? (unsigned char)(((const int*)tm_raw)[j] != 0)
                     : (unsigned char)(((const unsigned char*)tm_raw)[j] != 0);
    }
}

// ---------------- row L2-normalize; optional bf16 copy ----------------
__global__ __launch_bounds__(256) void norm_rows_k(const float* __restrict__ src,
                                                   float* __restrict__ dst,
                                                   short* __restrict__ dstb) {
    int row = blockIdx.x;
    const float* s = src + (size_t)row * DD;
    float v0 = s[threadIdx.x];
    float v1 = s[threadIdx.x + 256];
    float ss = v0 * v0 + v1 * v1;
    __shared__ float red[4];
    __shared__ float inv;
    float v = waveSum(ss);
    if ((threadIdx.x & 63) == 0) red[threadIdx.x >> 6] = v;
    __syncthreads();
    if (threadIdx.x == 0) inv = 1.0f / sqrtf(red[0] + red[1] + red[2] + red[3]);
    __syncthreads();
    float a = v0 * inv, b = v1 * inv;
    float* d = dst + (size_t)row * DD;
    d[threadIdx.x] = a;
    d[threadIdx.x + 256] = b;
    if (dstb) {
        short* db = dstb + (size_t)row * DD;
        db[threadIdx.x] = to_bf16(a);
        db[threadIdx.x + 256] = to_bf16(b);
    }
}

// ---------------- W column sq-norm partials ----------------
__global__ __launch_bounds__(128) void wsq_k(const float* __restrict__ W,
                                             float* __restrict__ swn_sq) {
    int c = blockIdx.x * 128 + threadIdx.x;
    if (c >= NCLS) return;
    int k0 = blockIdx.y * 64;
    float ss = 0.f;
    for (int k = k0; k < k0 + 64; k++) {
        float w = W[(size_t)k * NCLS + c];
        ss = fmaf(w, w, ss);
    }
    atomicAdd(&swn_sq[c], ss);
}

__global__ __launch_bounds__(256) void wfin_k(const float* __restrict__ swn_sq,
                                              float* __restrict__ swn) {
    int c = blockIdx.x * 256 + threadIdx.x;
    if (c < NCLS) swn[c] = SCALEF / sqrtf(swn_sq[c]);
}

// ---------------- W transpose + bf16 convert: W[512][NCLS] -> Wt[NCP][512] ----------------
__global__ __launch_bounds__(256) void wtrans_k(const float* __restrict__ W,
                                                short* __restrict__ Wt) {
    __shared__ short tile[32][66];
    int c0 = blockIdx.x * 64, k0 = blockIdx.y * 32;
    int t = threadIdx.x;
    int cl = t & 63, kl = t >> 6;  // kl 0..3
#pragma unroll
    for (int it = 0; it < 8; it++) {
        int k = k0 + kl + it * 4;
        int c = c0 + cl;
        float w = (c < NCLS) ? W[(size_t)k * NCLS + c] : 0.f;
        tile[kl + it * 4][cl] = to_bf16(w);
    }
    __syncthreads();
    int c_l = t >> 2, kc = (t & 3) * 8;
    bf16x8 v;
#pragma unroll
    for (int i = 0; i < 8; i++) v[i] = tile[kc + i][c_l];
    *(bf16x8*)(Wt + (size_t)(c0 + c_l) * DD + k0 + kc) = v;
}

// ---------------- logits via MFMA + sumexp ----------------
// Xb [512][512] bf16 (rows 0-255 vn, 256-511 tn); Wt [NCP][512] bf16.
// Wave computes 16 rows x 64 cols. grid = (NCP/64, 512/64), block = 256 (4 waves).
__global__ __launch_bounds__(256) void logits_mfma_k(const short* __restrict__ Xb,
                                                     const short* __restrict__ Wt,
                                                     const float* __restrict__ swn,
                                                     float* __restrict__ sumexp) {
    int wave = threadIdx.x >> 6;
    int lane = threadIdx.x & 63;
    int l15 = lane & 15, lh = lane >> 4;
    int row0 = blockIdx.y * 64 + wave * 16;
    int col0 = blockIdx.x * 64;
    f32x4 acc0 = {0.f, 0.f, 0.f, 0.f};
    f32x4 acc1 = acc0, acc2 = acc0, acc3 = acc0;
    // A frag: lane holds A[row0+l15][kb + 8*lh + i]; B frag j: B[kb+8*lh+i][col0+16j+l15] = Wt[col][k]
    const short* ap = Xb + (size_t)(row0 + l15) * DD + lh * 8;
    const short* bp = Wt + (size_t)(col0 + l15) * DD + lh * 8;
#pragma unroll
    for (int kb = 0; kb < DD; kb += 32) {
        bf16x8 a = *(const bf16x8*)(ap + kb);
        bf16x8 b0 = *(const bf16x8*)(bp + kb);
        bf16x8 b1 = *(const bf16x8*)(bp + 16 * DD + kb);
        bf16x8 b2 = *(const bf16x8*)(bp + 32 * DD + kb);
        bf16x8 b3 = *(const bf16x8*)(bp + 48 * DD + kb);
        acc0 = __builtin_amdgcn_mfma_f32_16x16x32_bf16(a, b0, acc0, 0, 0, 0);
        acc1 = __builtin_amdgcn_mfma_f32_16x16x32_bf16(a, b1, acc1, 0, 0, 0);
        acc2 = __builtin_amdgcn_mfma_f32_16x16x32_bf16(a, b2, acc2, 0, 0, 0);
        acc3 = __builtin_amdgcn_mfma_f32_16x16x32_bf16(a, b3, acc3, 0, 0, 0);
    }
    // D[i][j]: row = row0 + 4*lh + r, col = col0 + 16*j + l15
    float s0 = 0.f, s1 = 0.f, s2 = 0.f, s3 = 0.f;
#pragma unroll
    for (int j = 0; j < 4; j++) {
        int c = col0 + 16 * j + l15;
        bool valid = c < NCLS;
        float sc = valid ? swn[c] : 0.f;
        f32x4 accj = (j == 0) ? acc0 : (j == 1) ? acc1 : (j == 2) ? acc2 : acc3;
        s0 += valid ? __expf(accj[0] * sc) : 0.f;
        s1 += valid ? __expf(accj[1] * sc) : 0.f;
        s2 += valid ? __expf(accj[2] * sc) : 0.f;
        s3 += valid ? __expf(accj[3] * sc) : 0.f;
    }
#pragma unroll
    for (int o = 1; o < 16; o <<= 1) {
        s0 += __shfl_xor(s0, o);
        s1 += __shfl_xor(s1, o);
        s2 += __shfl_xor(s2, o);
        s3 += __shfl_xor(s3, o);
    }
    if (l15 == 0) {
        int rbase = row0 + 4 * lh;
        atomicAdd(&sumexp[rbase + 0], s0);
        atomicAdd(&sumexp[rbase + 1], s1);
        atomicAdd(&sumexp[rbase + 2], s2);
        atomicAdd(&sumexp[rbase + 3], s3);
    }
}

// ---------------- per-sample label logit (exact fp32) + instance loss ----------------
__global__ __launch_bounds__(256) void inst_label_k(const float* __restrict__ Xn,
                                                    const float* __restrict__ W,
                                                    const float* __restrict__ swn,
                                                    const float* __restrict__ sumexp,
                                                    const int* __restrict__ labs,
                                                    double* __restrict__ iacc) {
    int i = blockIdx.x;
    int t = threadIdx.x;
    int lab = labs[i];
    float dv = 0.f, dt_ = 0.f;
    for (int k = t; k < DD; k += 256) {
        float w = W[(size_t)k * NCLS + lab];
        dv = fmaf(Xn[(size_t)i * DD + k], w, dv);
        dt_ = fmaf(Xn[(size_t)(BB + i) * DD + k], w, dt_);
    }
    __shared__ float rv[4], rt[4];
    float a = waveSum(dv), b = waveSum(dt_);
    if ((t & 63) == 0) { rv[t >> 6] = a; rt[t >> 6] = b; }
    __syncthreads();
    if (t == 0) {
        float sc = swn[lab];
        float dvs = (rv[0] + rv[1] + rv[2] + rv[3]) * sc;
        float dts = (rt[0] + rt[1] + rt[2] + rt[3]) * sc;
        float li = (logf(sumexp[i]) - dvs) + (logf(sumexp[BB + i]) - dts);
        atomicAdd(iacc, (double)li);
    }
}

// ---------------- mask loss ----------------
__global__ __launch_bounds__(256) void mask_loss_k(const float* __restrict__ seg,
                                                   const int* __restrict__ masks,
                                                   double* __restrict__ acc) {
    int idx = blockIdx.x * 256 + threadIdx.x;
    int n = idx >> 12;
    int pix = idx & 4095;
    const float* p = seg + (size_t)n * SEGC * 4096 + pix;
    float x0 = p[0], x1 = p[4096], x2 = p[8192];
    float x3 = p[12288], x4 = p[16384], x5 = p[20480];
    float mx = fmaxf(fmaxf(fmaxf(x0, x1), fmaxf(x2, x3)), fmaxf(x4, x5));
    float se = __expf(x0 - mx) + __expf(x1 - mx) + __expf(x2 - mx) +
               __expf(x3 - mx) + __expf(x4 - mx) + __expf(x5 - mx);
    int m = masks[idx];
    float xm = (m == 0) ? x0 : (m == 1) ? x1 : (m == 2) ? x2
             : (m == 3) ? x3 : (m == 4) ? x4 : x5;
    float ce = logf(se) + mx - xm;
    __shared__ float red[4];
    float v = waveSum(ce);
    if ((threadIdx.x & 63) == 0) red[threadIdx.x >> 6] = v;
    __syncthreads();
    if (threadIdx.x == 0)
        atomicAdd(&acc[blockIdx.x & 63], (double)(red[0] + red[1] + red[2] + red[3]));
}

// ---------------- sim matrices ----------------
__global__ __launch_bounds__(256) void sim_k(const float* __restrict__ vn,
                                             const float* __restrict__ tn,
                                             const float* __restrict__ pn,
                                             const float* __restrict__ an,
                                             float* __restrict__ sims) {
    int z = blockIdx.z;
    const float* X;
    const float* Y;
    if (z == 0) { X = vn; Y = tn; }
    else { X = pn + (size_t)(z - 1) * BB * DD; Y = an + (size_t)(z - 1) * BB * DD; }
    float* C = sims + (size_t)z * BB * BB;
    int row0 = blockIdx.y * 32, col0 = blockIdx.x * 32;
    int tx = threadIdx.x & 15, ty = threadIdx.x >> 4;
    __shared__ float Xs[32][33], Ys[32][33];
    float a00 = 0, a01 = 0, a10 = 0, a11 = 0;
    for (int kc = 0; kc < DD; kc += 32) {
#pragma unroll
        for (int l = 0; l < 4; l++) {
            int idx = threadIdx.x + l * 256;
            int r = idx >> 5, kk = idx & 31;
            Xs[r][kk] = X[(size_t)(row0 + r) * DD + kc + kk];
            Ys[r][kk] = Y[(size_t)(col0 + r) * DD + kc + kk];
        }
        __syncthreads();
#pragma unroll
        for (int kk = 0; kk < 32; kk++) {
            float x0 = Xs[ty * 2][kk], x1 = Xs[ty * 2 + 1][kk];
            float y0 = Ys[tx * 2][kk], y1 = Ys[tx * 2 + 1][kk];
            a00 = fmaf(x0, y0, a00);
            a01 = fmaf(x0, y1, a01);
            a10 = fmaf(x1, y0, a10);
            a11 = fmaf(x1, y1, a11);
        }
        __syncthreads();
    }
    int r = row0 + ty * 2, c = col0 + tx * 2;
    C[(size_t)r * BB + c] = a00;
    C[(size_t)r * BB + c + 1] = a01;
    C[(size_t)(r + 1) * BB + c] = a10;
    C[(size_t)(r + 1) * BB + c + 1] = a11;
}

// ---------------- top-8 boost flags per part ----------------
__global__ __launch_bounds__(256) void boost_k(const float* __restrict__ sims,
                                               unsigned char* __restrict__ b1,
                                               unsigned char* __restrict__ b2) {
    int i = blockIdx.x;
    const float* S = sims + (size_t)(i + 1) * BB * BB;
    int c = threadIdx.x;
    __shared__ float rowv[BB], colv[BB];
    rowv[c] = S[(size_t)i * BB + c];
    colv[c] = S[(size_t)c * BB + i];
    __syncthreads();
    float rv = rowv[c], cv = colv[c];
    int rank1 = 0, rank2 = 0;
    for (int j = 0; j < BB; j++) {
        rank1 += rowv[j] > rv;
        rank2 += colv[j] > cv;
    }
    unsigned char bo1 = 0, bo2 = 0;
    if (rank1 < 8) {
        int cnt = 0;
        for (int a = 0; a < BB; a++) cnt += S[(size_t)a * BB + c] > rv;
        bo1 = (cnt < 8);
    }
    if (rank2 < 8) {
        int cnt = 0;
        for (int b = 0; b < BB; b++) cnt += S[(size_t)c * BB + b] > cv;
        bo2 = (cnt < 8);
    }
    b1[i * BB + c] = bo1;
    b2[i * BB + c] = bo2;
}

// ---------------- global align ----------------
__global__ __launch_bounds__(256) void galign_k(const float* __restrict__ sim,
                                                const int* __restrict__ labs,
                                                double* __restrict__ acc) {
    int r = blockIdx.x, c = threadIdx.x;
    float s = sim[(size_t)r * BB + c];
    float x = (labs[r] == labs[c]) ? (-SPF * (s - ALPHAF)) : (SNF * (s - BETAF));
    float v = softplusf(x);
    __shared__ float red[4];
    v = waveSum(v);
    if ((threadIdx.x & 63) == 0) red[threadIdx.x >> 6] = v;
    __syncthreads();
    if (threadIdx.x == 0)
        atomicAdd(&acc[blockIdx.x & 7], (double)(red[0] + red[1] + red[2] + red[3]));
}

// ---------------- local align ----------------
__global__ __launch_bounds__(256) void lalign_k(const float* __restrict__ sims,
                                                const int* __restrict__ labs,
                                                const unsigned char* __restrict__ vmb,
                                                const unsigned char* __restrict__ tmb,
                                                const unsigned char* __restrict__ b1,
                                                const unsigned char* __restrict__ b2,
                                                double* __restrict__ acc) {
    int i = blockIdx.y, r = blockIdx.x, c = threadIdx.x;
    const float* S = sims + (size_t)(i + 1) * BB * BB;
    float s = S[(size_t)r * BB + c];
    bool m = labs[r] == labs[c];
    float Lp = softplusf(-SPF * (s - ALPHAF));
    float Ln = softplusf(SNF * (s - BETAF));
    bool pmr = vmb[r * PP + i] != 0;
    bool pmc = vmb[c * PP + i] != 0;
    bool amc = tmb[c * PP + i] != 0;
    float v = 0.f;
    if (pmr && amc) v += (m || (b1[i * BB + c] != 0)) ? Lp : Ln;
    if (pmc && amc && pmr) v += (m || (b2[i * BB + r] != 0)) ? Lp : Ln;
    __shared__ float red[4];
    v = waveSum(v);
    if ((threadIdx.x & 63) == 0) red[threadIdx.x >> 6] = v;
    __syncthreads();
    if (threadIdx.x == 0)
        atomicAdd(&acc[blockIdx.x & 7], (double)(red[0] + red[1] + red[2] + red[3]));
}

// ---------------- finalize ----------------
// accs: [0..63] mask, [64..71] global, [72..79] local, [80] instance
__global__ void finalize_k(const double* __restrict__ accs, float* __restrict__ out) {
    int t = threadIdx.x;  // 64 threads
    double mv = accs[t];
    double gv = (t < 8) ? accs[64 + t] : 0.0;
    double lv = (t < 8) ? accs[72 + t] : 0.0;
#pragma unroll
    for (int o = 32; o; o >>= 1) {
        mv += __shfl_down(mv, o);
        gv += __shfl_down(gv, o);
        lv += __shfl_down(lv, o);
    }
    if (t == 0) {
        out[0] = (float)(accs[80] / (double)BB);
        out[1] = (float)((double)PP * mv / 5242880.0);
        out[2] = (float)(2.0 * gv / (double)BB);
        out[3] = (float)(lv / (double)(BB * PP));
    }
}

extern "C" void kernel_launch(void* const* d_in, const int* in_sizes, int n_in,
                              void* d_out, int out_size, void* d_ws, size_t ws_size,
                              hipStream_t stream) {
    const float* visual  = (const float*)d_in[0];
    const float* textual = (const float*)d_in[1];
    const float* part    = (const float*)d_in[2];
    const float* attr    = (const float*)d_in[3];
    const float* seg     = (const float*)d_in[4];
    const float* W       = (const float*)d_in[5];
    const void*  labels  = d_in[6];
    const int*   masks   = (const int*)d_in[7];
    const void*  vmask   = d_in[8];
    const void*  tmask   = d_in[9];
    float* out = (float*)d_out;

    float* ws = (float*)d_ws;
    // 16B-aligned layout (all chunk sizes are multiples of 4 floats)
    short* Wt   = (short*)ws;                          // NCP*512 bf16 = 2,818,048 floats
    float* base = ws + (size_t)NCP * DD / 2;
    short* Xb   = (short*)base;                        // 512*512 bf16 = 131,072 floats
    float* vn   = base + (size_t)BB * DD;              // (after Xb's 131072 floats) -- note: Xb occupies BB*DD floats
    float* tn   = vn + (size_t)BB * DD;
    float* pn   = tn + (size_t)BB * DD;
    float* an   = pn + (size_t)PP * BB * DD;
    float* swn  = an + (size_t)PP * BB * DD;           // NCP
    float* swn_sq = swn + NCP;                         // NCP
    float* sims = swn_sq + NCP;                        // 6*65536
    float* sumexp = sims + 6 * BB * BB;                // 512
    int* labs = (int*)(sumexp + 2 * BB);               // 256
    unsigned char* vmb = (unsigned char*)(labs + BB);  // 1280
    unsigned char* tmb = vmb + BB * PP;
    unsigned char* b1  = tmb + BB * PP;
    unsigned char* b2  = b1 + BB * PP;
    uintptr_t aaddr = ((uintptr_t)(b2 + BB * PP) + 15) & ~(uintptr_t)15;
    double* accs = (double*)aaddr;                     // 81 doubles

    hipMemsetAsync(sumexp, 0, 2 * BB * sizeof(float), stream);
    hipMemsetAsync(swn_sq, 0, NCP * sizeof(float), stream);
    hipMemsetAsync(accs, 0, 81 * sizeof(double), stream);

    convert_k<<<1, 256, 0, stream>>>(labels, vmask, tmask, labs, vmb, tmb);

    norm_rows_k<<<BB, 256, 0, stream>>>(visual, vn, Xb);
    norm_rows_k<<<BB, 256, 0, stream>>>(textual, tn, Xb + (size_t)BB * DD);
    norm_rows_k<<<PP * BB, 256, 0, stream>>>(part, pn, nullptr);
    norm_rows_k<<<PP * BB, 256, 0, stream>>>(attr, an, nullptr);

    dim3 wg(86, 8);
    wsq_k<<<wg, 128, 0, stream>>>(W, swn_sq);
    wfin_k<<<NCP / 256, 256, 0, stream>>>(swn_sq, swn);
    dim3 tg(NCP / 64, 16);
    wtrans_k<<<tg, 256, 0, stream>>>(W, Wt);

    dim3 mg(NCP / 64, 8);
    logits_mfma_k<<<mg, 256, 0, stream>>>(Xb, Wt, swn, sumexp);
    inst_label_k<<<BB, 256, 0, stream>>>(vn, W, swn, sumexp, labs, accs + 80);

    mask_loss_k<<<5242880 / 256, 256, 0, stream>>>(seg, masks, accs);

    dim3 sg(8, 8, 6);
    sim_k<<<sg, 256, 0, stream>>>(vn, tn, pn, an, sims);
    boost_k<<<PP, 256, 0, stream>>>(sims, b1, b2);

    galign_k<<<BB, 256, 0, stream>>>(sims, labs, accs + 64);
    dim3 lg(BB, PP);
    lalign_k<<<lg, 256, 0, stream>>>(sims, labs, vmb, tmb, b1, b2, accs + 72);

    finalize_k<<<1, 64, 0, stream>>>(accs, out);
}

// Round 8
// 386.680 us; speedup vs baseline: 2.3402x; 1.1018x over previous
//
#include <hip/hip_runtime.h>
#include <stdint.h>
#include <stddef.h>

#define BB 256
#define DD 512
#define PP 5
#define NCLS 11003
#define NCP 11008   // padded to 172*64
#define SEGC 6
#define SCALEF 28.0f
#define ALPHAF 0.6f
#define BETAF 0.4f
#define SPF 10.0f
#define SNF 40.0f

typedef __attribute__((ext_vector_type(8))) short bf16x8;
typedef __attribute__((ext_vector_type(4))) float f32x4;

__device__ __forceinline__ float waveSum(float v) {
#pragma unroll
    for (int o = 32; o; o >>= 1) v += __shfl_down(v, o);
    return v;
}

__device__ __forceinline__ float softplusf(float x) {
    return fmaxf(x, 0.f) + log1pf(__expf(-fabsf(x)));
}

__device__ __forceinline__ short to_bf16(float f) {
    uint32_t u = __float_as_uint(f);
    uint32_t r = (u + 0x7FFFu + ((u >> 16) & 1u)) >> 16;
    return (short)r;
}

// ---------------- dtype detection / conversion ----------------
__global__ __launch_bounds__(256) void convert_k(const void* labels_raw,
                                                 const void* vm_raw,
                                                 const void* tm_raw,
                                                 int* __restrict__ labs,
                                                 unsigned char* __restrict__ vmb,
                                                 unsigned char* __restrict__ tmb) {
    __shared__ int is64, v32, t32;
    if (threadIdx.x == 0) {
        const int* L = (const int*)labels_raw;
        int f = 1;
        for (int j = 0; j < 16; j++) if (L[2 * j + 1] != 0) f = 0;
        is64 = f;
        const int* V = (const int*)vm_raw;
        f = 1;
        for (int j = 0; j < 16; j++) if ((unsigned)V[j] > 1u) f = 0;
        v32 = f;
        const int* T = (const int*)tm_raw;
        f = 1;
        for (int j = 0; j < 16; j++) if ((unsigned)T[j] > 1u) f = 0;
        t32 = f;
    }
    __syncthreads();
    int i = threadIdx.x;
    if (i < BB) {
        if (is64) labs[i] = (int)((const long long*)labels_raw)[i];
        else      labs[i] = ((const int*)labels_raw)[i];
    }
    for (int j = i; j < BB * PP; j += 256) {
        vmb[j] = v32 ? (unsigned char)(((const int*)vm_raw)[j] != 0)
                     : (unsigned char)(((const unsigned char*)vm_raw)[j] != 0);
        tmb[j] = t32 ? (unsigned char)(((const int*)tm_raw)[j] != 0)
                     : (unsigned char)(((const unsigned char*)tm_raw)[j] != 0);
    }
}

// ---------------- row L2-normalize; optional MFMA-fragment-packed bf16 copy ----------------
// Packed layout: Xp[((rt*16 + kt)*64 + lane)*8 + i] = row rt*16+(lane&15), k kt*32+(lane>>4)*8+i
__global__ __launch_bounds__(256) void norm_rows_k(const float* __restrict__ src,
                                                   float* __restrict__ dst,
                                                   short* __restrict__ Xp,
                                                   int row_base) {
    int row = blockIdx.x;
    const float* s = src + (size_t)row * DD;
    float v0 = s[threadIdx.x];
    float v1 = s[threadIdx.x + 256];
    float ss = v0 * v0 + v1 * v1;
    __shared__ float red[4];
    __shared__ float inv;
    float v = waveSum(ss);
    if ((threadIdx.x & 63) == 0) red[threadIdx.x >> 6] = v;
    __syncthreads();
    if (threadIdx.x == 0) inv = 1.0f / sqrtf(red[0] + red[1] + red[2] + red[3]);
    __syncthreads();
    float a = v0 * inv, b = v1 * inv;
    float* d = dst + (size_t)row * DD;
    d[threadIdx.x] = a;
    d[threadIdx.x + 256] = b;
    if (Xp) {
        int prow = row_base + row;
        int rt = prow >> 4, rl = prow & 15;
#pragma unroll
        for (int h = 0; h < 2; h++) {
            int c = threadIdx.x + h * 256;
            float val = h ? b : a;
            int kt = c >> 5;
            int lh = (c & 31) >> 3;
            int i = c & 7;
            int lane = (lh << 4) | rl;
            Xp[((size_t)(rt * 16 + kt) * 64 + lane) * 8 + i] = to_bf16(val);
        }
    }
}

// ---------------- W column sq-norm partials ----------------
__global__ __launch_bounds__(128) void wsq_k(const float* __restrict__ W,
                                             float* __restrict__ swn_sq) {
    int c = blockIdx.x * 128 + threadIdx.x;
    if (c >= NCLS) return;
    int k0 = blockIdx.y * 64;
    float ss = 0.f;
    for (int k = k0; k < k0 + 64; k++) {
        float w = W[(size_t)k * NCLS + c];
        ss = fmaf(w, w, ss);
    }
    atomicAdd(&swn_sq[c], ss);
}

// ---------------- W -> fragment-packed bf16 Wp ----------------
// Wp[((ct*16 + kt)*64 + lane)*8 + i] = W[kt*32+(lane>>4)*8+i][ct*16+(lane&15)]
// grid (NCP/64, 16), block 256. Block: cols c0=bx*64 (4 col-tiles), k-tile kt=by.
__global__ __launch_bounds__(256) void wtrans_k(const float* __restrict__ W,
                                                short* __restrict__ Wp) {
    __shared__ short tile[32][66];
    int c0 = blockIdx.x * 64, k0 = blockIdx.y * 32;
    int t = threadIdx.x;
    int cl64 = t & 63, kl = t >> 6;  // kl 0..3
#pragma unroll
    for (int it = 0; it < 8; it++) {
        int k = k0 + kl + it * 4;
        int c = c0 + cl64;
        float w = (c < NCLS) ? W[(size_t)k * NCLS + c] : 0.f;
        tile[kl + it * 4][cl64] = to_bf16(w);
    }
    __syncthreads();
    int ctl = t >> 6, lane = t & 63;
    int cl = lane & 15, lh = lane >> 4;
    bf16x8 v;
#pragma unroll
    for (int i = 0; i < 8; i++) v[i] = tile[lh * 8 + i][ctl * 16 + cl];
    int ct = blockIdx.x * 4 + ctl;
    *(bf16x8*)(Wp + ((size_t)(ct * 16 + blockIdx.y) * 64 + lane) * 8) = v;
}

// ---------------- logits via MFMA + sumexp (fragment-packed operands) ----------------
// grid = (NCP/64, 8), block = 256 (4 waves). Wave: 16 rows x 64 cols.
__global__ __launch_bounds__(256) void logits_mfma_k(const short* __restrict__ Xp,
                                                     const short* __restrict__ Wp,
                                                     const float* __restrict__ swn_sq,
                                                     float* __restrict__ sumexp) {
    int wave = threadIdx.x >> 6;
    int lane = threadIdx.x & 63;
    int l15 = lane & 15, lh = lane >> 4;
    int rt = blockIdx.y * 4 + wave;     // row-tile (16 rows)
    int ct0 = blockIdx.x * 4;           // first of 4 col-tiles
    f32x4 acc0 = {0.f, 0.f, 0.f, 0.f};
    f32x4 acc1 = acc0, acc2 = acc0, acc3 = acc0;
    const short* ap = Xp + (size_t)rt * 16 * 64 * 8 + lane * 8;
    const short* bp = Wp + (size_t)ct0 * 16 * 64 * 8 + lane * 8;
#pragma unroll
    for (int kt = 0; kt < 16; kt++) {
        bf16x8 a  = *(const bf16x8*)(ap + (size_t)kt * 512);
        bf16x8 b0 = *(const bf16x8*)(bp + (size_t)kt * 512);
        bf16x8 b1 = *(const bf16x8*)(bp + (size_t)(16 * 512) + kt * 512);
        bf16x8 b2 = *(const bf16x8*)(bp + (size_t)(32 * 512) + kt * 512);
        bf16x8 b3 = *(const bf16x8*)(bp + (size_t)(48 * 512) + kt * 512);
        acc0 = __builtin_amdgcn_mfma_f32_16x16x32_bf16(a, b0, acc0, 0, 0, 0);
        acc1 = __builtin_amdgcn_mfma_f32_16x16x32_bf16(a, b1, acc1, 0, 0, 0);
        acc2 = __builtin_amdgcn_mfma_f32_16x16x32_bf16(a, b2, acc2, 0, 0, 0);
        acc3 = __builtin_amdgcn_mfma_f32_16x16x32_bf16(a, b3, acc3, 0, 0, 0);
    }
    // D[r][j]: row = rt*16 + 4*lh + r, col = (ct0+j)*16 + l15
    float s0 = 0.f, s1 = 0.f, s2 = 0.f, s3 = 0.f;
#pragma unroll
    for (int j = 0; j < 4; j++) {
        int c = (ct0 + j) * 16 + l15;
        bool valid = c < NCLS;
        float sc = valid ? SCALEF / sqrtf(swn_sq[c]) : 0.f;
        f32x4 accj = (j == 0) ? acc0 : (j == 1) ? acc1 : (j == 2) ? acc2 : acc3;
        s0 += valid ? __expf(accj[0] * sc) : 0.f;
        s1 += valid ? __expf(accj[1] * sc) : 0.f;
        s2 += valid ? __expf(accj[2] * sc) : 0.f;
        s3 += valid ? __expf(accj[3] * sc) : 0.f;
    }
#pragma unroll
    for (int o = 1; o < 16; o <<= 1) {
        s0 += __shfl_xor(s0, o);
        s1 += __shfl_xor(s1, o);
        s2 += __shfl_xor(s2, o);
        s3 += __shfl_xor(s3, o);
    }
    if (l15 == 0) {
        int rbase = rt * 16 + 4 * lh;
        atomicAdd(&sumexp[rbase + 0], s0);
        atomicAdd(&sumexp[rbase + 1], s1);
        atomicAdd(&sumexp[rbase + 2], s2);
        atomicAdd(&sumexp[rbase + 3], s3);
    }
}

// ---------------- per-sample label logit (exact fp32) + instance loss ----------------
__global__ __launch_bounds__(256) void inst_label_k(const float* __restrict__ Xn,
                                                    const float* __restrict__ W,
                                                    const float* __restrict__ swn_sq,
                                                    const float* __restrict__ sumexp,
                                                    const int* __restrict__ labs,
                                                    double* __restrict__ iacc) {
    int i = blockIdx.x;
    int t = threadIdx.x;
    int lab = labs[i];
    float dv = 0.f, dt_ = 0.f;
    for (int k = t; k < DD; k += 256) {
        float w = W[(size_t)k * NCLS + lab];
        dv = fmaf(Xn[(size_t)i * DD + k], w, dv);
        dt_ = fmaf(Xn[(size_t)(BB + i) * DD + k], w, dt_);
    }
    __shared__ float rv[4], rt[4];
    float a = waveSum(dv), b = waveSum(dt_);
    if ((t & 63) == 0) { rv[t >> 6] = a; rt[t >> 6] = b; }
    __syncthreads();
    if (t == 0) {
        float sc = SCALEF / sqrtf(swn_sq[lab]);
        float dvs = (rv[0] + rv[1] + rv[2] + rv[3]) * sc;
        float dts = (rt[0] + rt[1] + rt[2] + rt[3]) * sc;
        float li = (logf(sumexp[i]) - dvs) + (logf(sumexp[BB + i]) - dts);
        atomicAdd(iacc, (double)li);
    }
}

// ---------------- mask loss ----------------
__global__ __launch_bounds__(256) void mask_loss_k(const float* __restrict__ seg,
                                                   const int* __restrict__ masks,
                                                   double* __restrict__ acc) {
    int idx = blockIdx.x * 256 + threadIdx.x;
    int n = idx >> 12;
    int pix = idx & 4095;
    const float* p = seg + (size_t)n * SEGC * 4096 + pix;
    float x0 = p[0], x1 = p[4096], x2 = p[8192];
    float x3 = p[12288], x4 = p[16384], x5 = p[20480];
    float mx = fmaxf(fmaxf(fmaxf(x0, x1), fmaxf(x2, x3)), fmaxf(x4, x5));
    float se = __expf(x0 - mx) + __expf(x1 - mx) + __expf(x2 - mx) +
               __expf(x3 - mx) + __expf(x4 - mx) + __expf(x5 - mx);
    int m = masks[idx];
    float xm = (m == 0) ? x0 : (m == 1) ? x1 : (m == 2) ? x2
             : (m == 3) ? x3 : (m == 4) ? x4 : x5;
    float ce = logf(se) + mx - xm;
    __shared__ float red[4];
    float v = waveSum(ce);
    if ((threadIdx.x & 63) == 0) red[threadIdx.x >> 6] = v;
    __syncthreads();
    if (threadIdx.x == 0)
        atomicAdd(&acc[blockIdx.x & 63], (double)(red[0] + red[1] + red[2] + red[3]));
}

// ---------------- sim matrices ----------------
__global__ __launch_bounds__(256) void sim_k(const float* __restrict__ vn,
                                             const float* __restrict__ tn,
                                             const float* __restrict__ pn,
                                             const float* __restrict__ an,
                                             float* __restrict__ sims) {
    int z = blockIdx.z;
    const float* X;
    const float* Y;
    if (z == 0) { X = vn; Y = tn; }
    else { X = pn + (size_t)(z - 1) * BB * DD; Y = an + (size_t)(z - 1) * BB * DD; }
    float* C = sims + (size_t)z * BB * BB;
    int row0 = blockIdx.y * 32, col0 = blockIdx.x * 32;
    int tx = threadIdx.x & 15, ty = threadIdx.x >> 4;
    __shared__ float Xs[32][33], Ys[32][33];
    float a00 = 0, a01 = 0, a10 = 0, a11 = 0;
    for (int kc = 0; kc < DD; kc += 32) {
#pragma unroll
        for (int l = 0; l < 4; l++) {
            int idx = threadIdx.x + l * 256;
            int r = idx >> 5, kk = idx & 31;
            Xs[r][kk] = X[(size_t)(row0 + r) * DD + kc + kk];
            Ys[r][kk] = Y[(size_t)(col0 + r) * DD + kc + kk];
        }
        __syncthreads();
#pragma unroll
        for (int kk = 0; kk < 32; kk++) {
            float x0 = Xs[ty * 2][kk], x1 = Xs[ty * 2 + 1][kk];
            float y0 = Ys[tx * 2][kk], y1 = Ys[tx * 2 + 1][kk];
            a00 = fmaf(x0, y0, a00);
            a01 = fmaf(x0, y1, a01);
            a10 = fmaf(x1, y0, a10);
            a11 = fmaf(x1, y1, a11);
        }
        __syncthreads();
    }
    int r = row0 + ty * 2, c = col0 + tx * 2;
    C[(size_t)r * BB + c] = a00;
    C[(size_t)r * BB + c + 1] = a01;
    C[(size_t)(r + 1) * BB + c] = a10;
    C[(size_t)(r + 1) * BB + c + 1] = a11;
}

// ---------------- top-8 boost flags per part ----------------
__global__ __launch_bounds__(256) void boost_k(const float* __restrict__ sims,
                                               unsigned char* __restrict__ b1,
                                               unsigned char* __restrict__ b2) {
    int i = blockIdx.x;
    const float* S = sims + (size_t)(i + 1) * BB * BB;
    int c = threadIdx.x;
    __shared__ float rowv[BB], colv[BB];
    rowv[c] = S[(size_t)i * BB + c];
    colv[c] = S[(size_t)c * BB + i];
    __syncthreads();
    float rv = rowv[c], cv = colv[c];
    int rank1 = 0, rank2 = 0;
    for (int j = 0; j < BB; j++) {
        rank1 += rowv[j] > rv;
        rank2 += colv[j] > cv;
    }
    unsigned char bo1 = 0, bo2 = 0;
    if (rank1 < 8) {
        int cnt = 0;
        for (int a = 0; a < BB; a++) cnt += S[(size_t)a * BB + c] > rv;
        bo1 = (cnt < 8);
    }
    if (rank2 < 8) {
        int cnt = 0;
        for (int b = 0; b < BB; b++) cnt += S[(size_t)c * BB + b] > cv;
        bo2 = (cnt < 8);
    }
    b1[i * BB + c] = bo1;
    b2[i * BB + c] = bo2;
}

// ---------------- global align ----------------
__global__ __launch_bounds__(256) void galign_k(const float* __restrict__ sim,
                                                const int* __restrict__ labs,
                                                double* __restrict__ acc) {
    int r = blockIdx.x, c = threadIdx.x;
    float s = sim[(size_t)r * BB + c];
    float x = (labs[r] == labs[c]) ? (-SPF * (s - ALPHAF)) : (SNF * (s - BETAF));
    float v = softplusf(x);
    __shared__ float red[4];
    v = waveSum(v);
    if ((threadIdx.x & 63) == 0) red[threadIdx.x >> 6] = v;
    __syncthreads();
    if (threadIdx.x == 0)
        atomicAdd(&acc[blockIdx.x & 7], (double)(red[0] + red[1] + red[2] + red[3]));
}

// ---------------- local align ----------------
__global__ __launch_bounds__(256) void lalign_k(const float* __restrict__ sims,
                                                const int* __restrict__ labs,
                                                const unsigned char* __restrict__ vmb,
                                                const unsigned char* __restrict__ tmb,
                                                const unsigned char* __restrict__ b1,
                                                const unsigned char* __restrict__ b2,
                                                double* __restrict__ acc) {
    int i = blockIdx.y, r = blockIdx.x, c = threadIdx.x;
    const float* S = sims + (size_t)(i + 1) * BB * BB;
    float s = S[(size_t)r * BB + c];
    bool m = labs[r] == labs[c];
    float Lp = softplusf(-SPF * (s - ALPHAF));
    float Ln = softplusf(SNF * (s - BETAF));
    bool pmr = vmb[r * PP + i] != 0;
    bool pmc = vmb[c * PP + i] != 0;
    bool amc = tmb[c * PP + i] != 0;
    float v = 0.f;
    if (pmr && amc) v += (m || (b1[i * BB + c] != 0)) ? Lp : Ln;
    if (pmc && amc && pmr) v += (m || (b2[i * BB + r] != 0)) ? Lp : Ln;
    __shared__ float red[4];
    v = waveSum(v);
    if ((threadIdx.x & 63) == 0) red[threadIdx.x >> 6] = v;
    __syncthreads();
    if (threadIdx.x == 0)
        atomicAdd(&acc[blockIdx.x & 7], (double)(red[0] + red[1] + red[2] + red[3]));
}

// ---------------- finalize ----------------
// accs: [0..63] mask, [64..71] global, [72..79] local, [80] instance
__global__ void finalize_k(const double* __restrict__ accs, float* __restrict__ out) {
    int t = threadIdx.x;  // 64 threads
    double mv = accs[t];
    double gv = (t < 8) ? accs[64 + t] : 0.0;
    double lv = (t < 8) ? accs[72 + t] : 0.0;
#pragma unroll
    for (int o = 32; o; o >>= 1) {
        mv += __shfl_down(mv, o);
        gv += __shfl_down(gv, o);
        lv += __shfl_down(lv, o);
    }
    if (t == 0) {
        out[0] = (float)(accs[80] / (double)BB);
        out[1] = (float)((double)PP * mv / 5242880.0);
        out[2] = (float)(2.0 * gv / (double)BB);
        out[3] = (float)(lv / (double)(BB * PP));
    }
}

extern "C" void kernel_launch(void* const* d_in, const int* in_sizes, int n_in,
                              void* d_out, int out_size, void* d_ws, size_t ws_size,
                              hipStream_t stream) {
    const float* visual  = (const float*)d_in[0];
    const float* textual = (const float*)d_in[1];
    const float* part    = (const float*)d_in[2];
    const float* attr    = (const float*)d_in[3];
    const float* seg     = (const float*)d_in[4];
    const float* W       = (const float*)d_in[5];
    const void*  labels  = d_in[6];
    const int*   masks   = (const int*)d_in[7];
    const void*  vmask   = d_in[8];
    const void*  tmask   = d_in[9];
    float* out = (float*)d_out;

    float* ws = (float*)d_ws;
    short* Wp   = (short*)ws;                          // NCP*512 bf16 = 2,818,048 floats
    float* base = ws + (size_t)NCP * DD / 2;
    short* Xp   = (short*)base;                        // 512*512 bf16 = 131,072 floats
    float* vn   = base + (size_t)BB * DD;
    float* tn   = vn + (size_t)BB * DD;
    float* pn   = tn + (size_t)BB * DD;
    float* an   = pn + (size_t)PP * BB * DD;
    float* swn_sq = an + (size_t)PP * BB * DD;         // NCP
    float* sims = swn_sq + NCP;                        // 6*65536
    float* sumexp = sims + 6 * BB * BB;                // 512
    int* labs = (int*)(sumexp + 2 * BB);               // 256
    unsigned char* vmb = (unsigned char*)(labs + BB);  // 1280
    unsigned char* tmb = vmb + BB * PP;
    unsigned char* b1  = tmb + BB * PP;
    unsigned char* b2  = b1 + BB * PP;
    uintptr_t aaddr = ((uintptr_t)(b2 + BB * PP) + 15) & ~(uintptr_t)15;
    double* accs = (double*)aaddr;                     // 81 doubles

    hipMemsetAsync(sumexp, 0, 2 * BB * sizeof(float), stream);
    hipMemsetAsync(swn_sq, 0, NCP * sizeof(float), stream);
    hipMemsetAsync(accs, 0, 81 * sizeof(double), stream);

    convert_k<<<1, 256, 0, stream>>>(labels, vmask, tmask, labs, vmb, tmb);

    norm_rows_k<<<BB, 256, 0, stream>>>(visual, vn, Xp, 0);
    norm_rows_k<<<BB, 256, 0, stream>>>(textual, tn, Xp, BB);
    norm_rows_k<<<PP * BB, 256, 0, stream>>>(part, pn, nullptr, 0);
    norm_rows_k<<<PP * BB, 256, 0, stream>>>(attr, an, nullptr, 0);

    dim3 wg(86, 8);
    wsq_k<<<wg, 128, 0, stream>>>(W, swn_sq);
    dim3 tg(NCP / 64, 16);
    wtrans_k<<<tg, 256, 0, stream>>>(W, Wp);

    dim3 mg(NCP / 64, 8);
    logits_mfma_k<<<mg, 256, 0, stream>>>(Xp, Wp, swn_sq, sumexp);
    inst_label_k<<<BB, 256, 0, stream>>>(vn, W, swn_sq, sumexp, labs, accs + 80);

    mask_loss_k<<<5242880 / 256, 256, 0, stream>>>(seg, masks, accs);

    dim3 sg(8, 8, 6);
    sim_k<<<sg, 256, 0, stream>>>(vn, tn, pn, an, sims);
    boost_k<<<PP, 256, 0, stream>>>(sims, b1, b2);

    galign_k<<<BB, 256, 0, stream>>>(sims, labs, accs + 64);
    dim3 lg(BB, PP);
    lalign_k<<<lg, 256, 0, stream>>>(sims, labs, vmb, tmb, b1, b2, accs + 72);

    finalize_k<<<1, 64, 0, stream>>>(accs, out);
}

// Round 10
// 373.164 us; speedup vs baseline: 2.4250x; 1.0362x over previous
//
#include <hip/hip_runtime.h>
#include <stdint.h>
#include <stddef.h>

#define BB 256
#define DD 512
#define PP 5
#define NCLS 11003
#define NCP 11008   // padded to 172*64
#define SEGC 6
#define SCALEF 28.0f
#define ALPHAF 0.6f
#define BETAF 0.4f
#define SPF 10.0f
#define SNF 40.0f

typedef __attribute__((ext_vector_type(8))) short bf16x8;
typedef __attribute__((ext_vector_type(4))) float f32x4;

__device__ __forceinline__ float waveSum(float v) {
#pragma unroll
    for (int o = 32; o; o >>= 1) v += __shfl_down(v, o);
    return v;
}

__device__ __forceinline__ float softplusf(float x) {
    return fmaxf(x, 0.f) + log1pf(__expf(-fabsf(x)));
}

__device__ __forceinline__ short to_bf16(float f) {
    uint32_t u = __float_as_uint(f);
    uint32_t r = (u + 0x7FFFu + ((u >> 16) & 1u)) >> 16;
    return (short)r;
}

// ---------------- dtype detection / conversion ----------------
__global__ __launch_bounds__(256) void convert_k(const void* labels_raw,
                                                 const void* vm_raw,
                                                 const void* tm_raw,
                                                 int* __restrict__ labs,
                                                 unsigned char* __restrict__ vmb,
                                                 unsigned char* __restrict__ tmb) {
    __shared__ int is64, v32, t32;
    if (threadIdx.x == 0) {
        const int* L = (const int*)labels_raw;
        int f = 1;
        for (int j = 0; j < 16; j++) if (L[2 * j + 1] != 0) f = 0;
        is64 = f;
        const int* V = (const int*)vm_raw;
        f = 1;
        for (int j = 0; j < 16; j++) if ((unsigned)V[j] > 1u) f = 0;
        v32 = f;
        const int* T = (const int*)tm_raw;
        f = 1;
        for (int j = 0; j < 16; j++) if ((unsigned)T[j] > 1u) f = 0;
        t32 = f;
    }
    __syncthreads();
    int i = threadIdx.x;
    if (i < BB) {
        if (is64) labs[i] = (int)((const long long*)labels_raw)[i];
        else      labs[i] = ((const int*)labels_raw)[i];
    }
    for (int j = i; j < BB * PP; j += 256) {
        vmb[j] = v32 ? (unsigned char)(((const int*)vm_raw)[j] != 0)
                     : (unsigned char)(((const unsigned char*)vm_raw)[j] != 0);
        tmb[j] = t32 ? (unsigned char)(((const int*)tm_raw)[j] != 0)
                     : (unsigned char)(((const unsigned char*)tm_raw)[j] != 0);
    }
}

// ---------------- row L2-normalize; optional MFMA-fragment-packed bf16 copy ----------------
// Packed layout: Xp[((rt*16 + kt)*64 + lane)*8 + i] = row rt*16+(lane&15), k kt*32+(lane>>4)*8+i
__global__ __launch_bounds__(256) void norm_rows_k(const float* __restrict__ src,
                                                   float* __restrict__ dst,
                                                   short* __restrict__ Xp,
                                                   int row_base) {
    int row = blockIdx.x;
    const float* s = src + (size_t)row * DD;
    float v0 = s[threadIdx.x];
    float v1 = s[threadIdx.x + 256];
    float ss = v0 * v0 + v1 * v1;
    __shared__ float red[4];
    __shared__ float inv;
    float v = waveSum(ss);
    if ((threadIdx.x & 63) == 0) red[threadIdx.x >> 6] = v;
    __syncthreads();
    if (threadIdx.x == 0) inv = 1.0f / sqrtf(red[0] + red[1] + red[2] + red[3]);
    __syncthreads();
    float a = v0 * inv, b = v1 * inv;
    float* d = dst + (size_t)row * DD;
    d[threadIdx.x] = a;
    d[threadIdx.x + 256] = b;
    if (Xp) {
        int prow = row_base + row;
        int rt = prow >> 4, rl = prow & 15;
#pragma unroll
        for (int h = 0; h < 2; h++) {
            int c = threadIdx.x + h * 256;
            float val = h ? b : a;
            int kt = c >> 5;
            int lh = (c & 31) >> 3;
            int i = c & 7;
            int lane = (lh << 4) | rl;
            Xp[((size_t)(rt * 16 + kt) * 64 + lane) * 8 + i] = to_bf16(val);
        }
    }
}

// ---------------- W -> fragment-packed bf16 Wp, fused column sq-norm partials ----------------
// Wp[((ct*16 + kt)*64 + lane)*8 + i] = W[kt*32+(lane>>4)*8+i][ct*16+(lane&15)]
// grid (NCP/64, 16), block 256.
__global__ __launch_bounds__(256) void wtrans_k(const float* __restrict__ W,
                                                short* __restrict__ Wp,
                                                float* __restrict__ swn_sq) {
    __shared__ short tile[32][66];
    __shared__ float colsum[64];
    int c0 = blockIdx.x * 64, k0 = blockIdx.y * 32;
    int t = threadIdx.x;
    if (t < 64) colsum[t] = 0.f;
    __syncthreads();
    int cl64 = t & 63, kl = t >> 6;  // kl 0..3
    float ss = 0.f;
#pragma unroll
    for (int it = 0; it < 8; it++) {
        int k = k0 + kl + it * 4;
        int c = c0 + cl64;
        float w = (c < NCLS) ? W[(size_t)k * NCLS + c] : 0.f;
        ss = fmaf(w, w, ss);
        tile[kl + it * 4][cl64] = to_bf16(w);
    }
    atomicAdd(&colsum[cl64], ss);
    __syncthreads();
    int ctl = t >> 6, lane = t & 63;
    int cl = lane & 15, lh = lane >> 4;
    bf16x8 v;
#pragma unroll
    for (int i = 0; i < 8; i++) v[i] = tile[lh * 8 + i][ctl * 16 + cl];
    int ct = blockIdx.x * 4 + ctl;
    *(bf16x8*)(Wp + ((size_t)(ct * 16 + blockIdx.y) * 64 + lane) * 8) = v;
    if (t < 64) atomicAdd(&swn_sq[c0 + t], colsum[t]);
}

// ---------------- logits via MFMA + sumexp (fragment-packed operands) ----------------
// grid = (NCP/64, 8), block = 256 (4 waves). Wave: 16 rows x 64 cols.
__global__ __launch_bounds__(256) void logits_mfma_k(const short* __restrict__ Xp,
                                                     const short* __restrict__ Wp,
                                                     const float* __restrict__ swn_sq,
                                                     float* __restrict__ sumexp) {
    int wave = threadIdx.x >> 6;
    int lane = threadIdx.x & 63;
    int l15 = lane & 15, lh = lane >> 4;
    int rt = blockIdx.y * 4 + wave;     // row-tile (16 rows)
    int ct0 = blockIdx.x * 4;           // first of 4 col-tiles
    f32x4 acc0 = {0.f, 0.f, 0.f, 0.f};
    f32x4 acc1 = acc0, acc2 = acc0, acc3 = acc0;
    const short* ap = Xp + (size_t)rt * 16 * 64 * 8 + lane * 8;
    const short* bp = Wp + (size_t)ct0 * 16 * 64 * 8 + lane * 8;
#pragma unroll
    for (int kt = 0; kt < 16; kt++) {
        bf16x8 a  = *(const bf16x8*)(ap + (size_t)kt * 512);
        bf16x8 b0 = *(const bf16x8*)(bp + (size_t)kt * 512);
        bf16x8 b1 = *(const bf16x8*)(bp + (size_t)(16 * 512) + kt * 512);
        bf16x8 b2 = *(const bf16x8*)(bp + (size_t)(32 * 512) + kt * 512);
        bf16x8 b3 = *(const bf16x8*)(bp + (size_t)(48 * 512) + kt * 512);
        acc0 = __builtin_amdgcn_mfma_f32_16x16x32_bf16(a, b0, acc0, 0, 0, 0);
        acc1 = __builtin_amdgcn_mfma_f32_16x16x32_bf16(a, b1, acc1, 0, 0, 0);
        acc2 = __builtin_amdgcn_mfma_f32_16x16x32_bf16(a, b2, acc2, 0, 0, 0);
        acc3 = __builtin_amdgcn_mfma_f32_16x16x32_bf16(a, b3, acc3, 0, 0, 0);
    }
    float s0 = 0.f, s1 = 0.f, s2 = 0.f, s3 = 0.f;
#pragma unroll
    for (int j = 0; j < 4; j++) {
        int c = (ct0 + j) * 16 + l15;
        bool valid = c < NCLS;
        float sc = valid ? SCALEF / sqrtf(swn_sq[c]) : 0.f;
        f32x4 accj = (j == 0) ? acc0 : (j == 1) ? acc1 : (j == 2) ? acc2 : acc3;
        s0 += valid ? __expf(accj[0] * sc) : 0.f;
        s1 += valid ? __expf(accj[1] * sc) : 0.f;
        s2 += valid ? __expf(accj[2] * sc) : 0.f;
        s3 += valid ? __expf(accj[3] * sc) : 0.f;
    }
#pragma unroll
    for (int o = 1; o < 16; o <<= 1) {
        s0 += __shfl_xor(s0, o);
        s1 += __shfl_xor(s1, o);
        s2 += __shfl_xor(s2, o);
        s3 += __shfl_xor(s3, o);
    }
    if (l15 == 0) {
        int rbase = rt * 16 + 4 * lh;
        atomicAdd(&sumexp[rbase + 0], s0);
        atomicAdd(&sumexp[rbase + 1], s1);
        atomicAdd(&sumexp[rbase + 2], s2);
        atomicAdd(&sumexp[rbase + 3], s3);
    }
}

// ---------------- per-sample label logit (exact fp32) + instance loss ----------------
__global__ __launch_bounds__(256) void inst_label_k(const float* __restrict__ Xn,
                                                    const float* __restrict__ W,
                                                    const float* __restrict__ swn_sq,
                                                    const float* __restrict__ sumexp,
                                                    const int* __restrict__ labs,
                                                    double* __restrict__ iacc) {
    int i = blockIdx.x;
    int t = threadIdx.x;
    int lab = labs[i];
    float dv = 0.f, dt_ = 0.f;
    for (int k = t; k < DD; k += 256) {
        float w = W[(size_t)k * NCLS + lab];
        dv = fmaf(Xn[(size_t)i * DD + k], w, dv);
        dt_ = fmaf(Xn[(size_t)(BB + i) * DD + k], w, dt_);
    }
    __shared__ float rv[4], rt[4];
    float a = waveSum(dv), b = waveSum(dt_);
    if ((t & 63) == 0) { rv[t >> 6] = a; rt[t >> 6] = b; }
    __syncthreads();
    if (t == 0) {
        float sc = SCALEF / sqrtf(swn_sq[lab]);
        float dvs = (rv[0] + rv[1] + rv[2] + rv[3]) * sc;
        float dts = (rt[0] + rt[1] + rt[2] + rt[3]) * sc;
        float li = (logf(sumexp[i]) - dvs) + (logf(sumexp[BB + i]) - dts);
        atomicAdd(iacc, (double)li);
    }
}

// ---------------- mask loss (4 pixels/thread, float4/int4) ----------------
__global__ __launch_bounds__(256) void mask_loss_k(const float* __restrict__ seg,
                                                   const int* __restrict__ masks,
                                                   double* __restrict__ acc) {
    int tid = blockIdx.x * 256 + threadIdx.x;   // < 1,310,720
    int n = tid >> 10;          // image index (B*P = 1280)
    int q = (tid & 1023) << 2;  // pixel base
    const float* p = seg + (size_t)n * (SEGC * 4096) + q;
    float4 x0 = *(const float4*)(p);
    float4 x1 = *(const float4*)(p + 4096);
    float4 x2 = *(const float4*)(p + 8192);
    float4 x3 = *(const float4*)(p + 12288);
    float4 x4 = *(const float4*)(p + 16384);
    float4 x5 = *(const float4*)(p + 20480);
    int4 mm = *(const int4*)(masks + (size_t)n * 4096 + q);
    float tot = 0.f;
#pragma unroll
    for (int j = 0; j < 4; j++) {
        float a0 = ((const float*)&x0)[j];
        float a1 = ((const float*)&x1)[j];
        float a2 = ((const float*)&x2)[j];
        float a3 = ((const float*)&x3)[j];
        float a4 = ((const float*)&x4)[j];
        float a5 = ((const float*)&x5)[j];
        int m = ((const int*)&mm)[j];
        float mx = fmaxf(fmaxf(fmaxf(a0, a1), fmaxf(a2, a3)), fmaxf(a4, a5));
        float se = __expf(a0 - mx) + __expf(a1 - mx) + __expf(a2 - mx) +
                   __expf(a3 - mx) + __expf(a4 - mx) + __expf(a5 - mx);
        float xm = (m == 0) ? a0 : (m == 1) ? a1 : (m == 2) ? a2
                 : (m == 3) ? a3 : (m == 4) ? a4 : a5;
        tot += logf(se) + mx - xm;
    }
    __shared__ float red[4];
    float v = waveSum(tot);
    if ((threadIdx.x & 63) == 0) red[threadIdx.x >> 6] = v;
    __syncthreads();
    if (threadIdx.x == 0)
        atomicAdd(&acc[blockIdx.x & 63], (double)(red[0] + red[1] + red[2] + red[3]));
}

// ---------------- sim matrices ----------------
__global__ __launch_bounds__(256) void sim_k(const float* __restrict__ vn,
                                             const float* __restrict__ tn,
                                             const float* __restrict__ pn,
                                             const float* __restrict__ an,
                                             float* __restrict__ sims) {
    int z = blockIdx.z;
    const float* X;
    const float* Y;
    if (z == 0) { X = vn; Y = tn; }
    else { X = pn + (size_t)(z - 1) * BB * DD; Y = an + (size_t)(z - 1) * BB * DD; }
    float* C = sims + (size_t)z * BB * BB;
    int row0 = blockIdx.y * 32, col0 = blockIdx.x * 32;
    int tx = threadIdx.x & 15, ty = threadIdx.x >> 4;
    __shared__ float Xs[32][33], Ys[32][33];
    float a00 = 0, a01 = 0, a10 = 0, a11 = 0;
    for (int kc = 0; kc < DD; kc += 32) {
#pragma unroll
        for (int l = 0; l < 4; l++) {
            int idx = threadIdx.x + l * 256;
            int r = idx >> 5, kk = idx & 31;
            Xs[r][kk] = X[(size_t)(row0 + r) * DD + kc + kk];
            Ys[r][kk] = Y[(size_t)(col0 + r) * DD + kc + kk];
        }
        __syncthreads();
#pragma unroll
        for (int kk = 0; kk < 32; kk++) {
            float x0 = Xs[ty * 2][kk], x1 = Xs[ty * 2 + 1][kk];
            float y0 = Ys[tx * 2][kk], y1 = Ys[tx * 2 + 1][kk];
            a00 = fmaf(x0, y0, a00);
            a01 = fmaf(x0, y1, a01);
            a10 = fmaf(x1, y0, a10);
            a11 = fmaf(x1, y1, a11);
        }
        __syncthreads();
    }
    int r = row0 + ty * 2, c = col0 + tx * 2;
    C[(size_t)r * BB + c] = a00;
    C[(size_t)r * BB + c + 1] = a01;
    C[(size_t)(r + 1) * BB + c] = a10;
    C[(size_t)(r + 1) * BB + c + 1] = a11;
}

// ---------------- top-8 boost flags per part ----------------
__global__ __launch_bounds__(256) void boost_k(const float* __restrict__ sims,
                                               unsigned char* __restrict__ b1,
                                               unsigned char* __restrict__ b2) {
    int i = blockIdx.x;
    const float* S = sims + (size_t)(i + 1) * BB * BB;
    int c = threadIdx.x;
    __shared__ float rowv[BB], colv[BB];
    rowv[c] = S[(size_t)i * BB + c];
    colv[c] = S[(size_t)c * BB + i];
    __syncthreads();
    float rv = rowv[c], cv = colv[c];
    int rank1 = 0, rank2 = 0;
    for (int j = 0; j < BB; j++) {
        rank1 += rowv[j] > rv;
        rank2 += colv[j] > cv;
    }
    unsigned char bo1 = 0, bo2 = 0;
    if (rank1 < 8) {
        int cnt = 0;
        for (int a = 0; a < BB; a++) cnt += S[(size_t)a * BB + c] > rv;
        bo1 = (cnt < 8);
    }
    if (rank2 < 8) {
        int cnt = 0;
        for (int b = 0; b < BB; b++) cnt += S[(size_t)c * BB + b] > cv;
        bo2 = (cnt < 8);
    }
    b1[i * BB + c] = bo1;
    b2[i * BB + c] = bo2;
}

// ---------------- local align (i<PP) + global align (i==PP) fused ----------------
__global__ __launch_bounds__(256) void lalign_k(const float* __restrict__ sims,
                                                const int* __restrict__ labs,
                                                const unsigned char* __restrict__ vmb,
                                                const unsigned char* __restrict__ tmb,
                                                const unsigned char* __restrict__ b1,
                                                const unsigned char* __restrict__ b2,
                                                double* __restrict__ accL,
                                                double* __restrict__ accG) {
    int i = blockIdx.y, r = blockIdx.x, c = threadIdx.x;
    float v = 0.f;
    if (i == PP) {
        float s = sims[(size_t)r * BB + c];
        float x = (labs[r] == labs[c]) ? (-SPF * (s - ALPHAF)) : (SNF * (s - BETAF));
        v = softplusf(x);
    } else {
        const float* S = sims + (size_t)(i + 1) * BB * BB;
        float s = S[(size_t)r * BB + c];
        bool m = labs[r] == labs[c];
        float Lp = softplusf(-SPF * (s - ALPHAF));
        float Ln = softplusf(SNF * (s - BETAF));
        bool pmr = vmb[r * PP + i] != 0;
        bool pmc = vmb[c * PP + i] != 0;
        bool amc = tmb[c * PP + i] != 0;
        if (pmr && amc) v += (m || (b1[i * BB + c] != 0)) ? Lp : Ln;
        if (pmc && amc && pmr) v += (m || (b2[i * BB + r] != 0)) ? Lp : Ln;
    }
    __shared__ float red[4];
    v = waveSum(v);
    if ((threadIdx.x & 63) == 0) red[threadIdx.x >> 6] = v;
    __syncthreads();
    if (threadIdx.x == 0) {
        double* dst = (i == PP) ? &accG[r & 7] : &accL[r & 7];
        atomicAdd(dst, (double)(red[0] + red[1] + red[2] + red[3]));
    }
}

// ---------------- finalize ----------------
// accs: [0..63] mask, [64..71] global, [72..79] local, [80] instance
__global__ void finalize_k(const double* __restrict__ accs, float* __restrict__ out) {
    int t = threadIdx.x;  // 64 threads
    double mv = accs[t];
    double gv = (t < 8) ? accs[64 + t] : 0.0;
    double lv = (t < 8) ? accs[72 + t] : 0.0;
#pragma unroll
    for (int o = 32; o; o >>= 1) {
        mv += __shfl_down(mv, o);
        gv += __shfl_down(gv, o);
        lv += __shfl_down(lv, o);
    }
    if (t == 0) {
        out[0] = (float)(accs[80] / (double)BB);
        out[1] = (float)((double)PP * mv / 5242880.0);
        out[2] = (float)(2.0 * gv / (double)BB);
        out[3] = (float)(lv / (double)(BB * PP));
    }
}

extern "C" void kernel_launch(void* const* d_in, const int* in_sizes, int n_in,
                              void* d_out, int out_size, void* d_ws, size_t ws_size,
                              hipStream_t stream) {
    const float* visual  = (const float*)d_in[0];
    const float* textual = (const float*)d_in[1];
    const float* part    = (const float*)d_in[2];
    const float* attr    = (const float*)d_in[3];
    const float* seg     = (const float*)d_in[4];
    const float* W       = (const float*)d_in[5];
    const void*  labels  = d_in[6];
    const int*   masks   = (const int*)d_in[7];
    const void*  vmask   = d_in[8];
    const void*  tmask   = d_in[9];
    float* out = (float*)d_out;

    float* ws = (float*)d_ws;
    short* Wp   = (short*)ws;                          // NCP*512 bf16
    float* base = ws + (size_t)NCP * DD / 2;
    short* Xp   = (short*)base;                        // 512*512 bf16 (= BB*DD floats)
    float* vn   = base + (size_t)BB * DD;
    float* tn   = vn + (size_t)BB * DD;
    float* pn   = tn + (size_t)BB * DD;
    float* an   = pn + (size_t)PP * BB * DD;
    float* swn_sq = an + (size_t)PP * BB * DD;         // NCP
    float* sims = swn_sq + NCP;                        // 6*65536
    float* sumexp = sims + 6 * BB * BB;                // 512
    int* labs = (int*)(sumexp + 2 * BB);               // 256
    unsigned char* vmb = (unsigned char*)(labs + BB);  // 1280
    unsigned char* tmb = vmb + BB * PP;
    unsigned char* b1  = tmb + BB * PP;
    unsigned char* b2  = b1 + BB * PP;
    uintptr_t aaddr = ((uintptr_t)(b2 + BB * PP) + 15) & ~(uintptr_t)15;
    double* accs = (double*)aaddr;                     // 81 doubles

    hipMemsetAsync(sumexp, 0, 2 * BB * sizeof(float), stream);
    hipMemsetAsync(swn_sq, 0, NCP * sizeof(float), stream);
    hipMemsetAsync(accs, 0, 81 * sizeof(double), stream);

    convert_k<<<1, 256, 0, stream>>>(labels, vmask, tmask, labs, vmb, tmb);

    norm_rows_k<<<BB, 256, 0, stream>>>(visual, vn, Xp, 0);
    norm_rows_k<<<BB, 256, 0, stream>>>(textual, tn, Xp, BB);
    norm_rows_k<<<PP * BB, 256, 0, stream>>>(part, pn, nullptr, 0);
    norm_rows_k<<<PP * BB, 256, 0, stream>>>(attr, an, nullptr, 0);

    dim3 tg(NCP / 64, 16);
    wtrans_k<<<tg, 256, 0, stream>>>(W, Wp, swn_sq);

    dim3 mg(NCP / 64, 8);
    logits_mfma_k<<<mg, 256, 0, stream>>>(Xp, Wp, swn_sq, sumexp);
    inst_label_k<<<BB, 256, 0, stream>>>(vn, W, swn_sq, sumexp, labs, accs + 80);

    mask_loss_k<<<1310720 / 256, 256, 0, stream>>>(seg, masks, accs);

    dim3 sg(8, 8, 6);
    sim_k<<<sg, 256, 0, stream>>>(vn, tn, pn, an, sims);
    boost_k<<<PP, 256, 0, stream>>>(sims, b1, b2);

    dim3 lg(BB, PP + 1);
    lalign_k<<<lg, 256, 0, stream>>>(sims, labs, vmb, tmb, b1, b2, accs + 72, accs + 64);

    finalize_k<<<1, 64, 0, stream>>>(accs, out);
}

// Round 11
// 343.067 us; speedup vs baseline: 2.6377x; 1.0877x over previous
//
#include <hip/hip_runtime.h>
#include <stdint.h>
#include <stddef.h>

#define BB 256
#define DD 512
#define PP 5
#define NCLS 11003
#define NCP 11008   // padded to 172*64
#define SEGC 6
#define SCALEF 28.0f
#define ALPHAF 0.6f
#define BETAF 0.4f
#define SPF 10.0f
#define SNF 40.0f

typedef __attribute__((ext_vector_type(8))) short bf16x8;
typedef __attribute__((ext_vector_type(4))) float f32x4;

__device__ __forceinline__ float waveSum(float v) {
#pragma unroll
    for (int o = 32; o; o >>= 1) v += __shfl_down(v, o);
    return v;
}

__device__ __forceinline__ float softplusf(float x) {
    return fmaxf(x, 0.f) + log1pf(__expf(-fabsf(x)));
}

__device__ __forceinline__ short to_bf16(float f) {
    uint32_t u = __float_as_uint(f);
    uint32_t r = (u + 0x7FFFu + ((u >> 16) & 1u)) >> 16;
    return (short)r;
}

// =================== LAYER A: prep (norms + W-pack + convert), all independent ===================
// blocks [0,3072): row-normalize vis/text/part/attr (+ bf16 fragment-pack vis/text into Xp)
// blocks [3072,5824): W -> Wp fragment pack + column sq-norm partials
// block 5824: dtype detect/convert labels + masks
__global__ __launch_bounds__(256) void prep_k(const float* __restrict__ vis,
                                              const float* __restrict__ text,
                                              const float* __restrict__ part,
                                              const float* __restrict__ attr,
                                              const float* __restrict__ W,
                                              const void* labels_raw,
                                              const void* vm_raw,
                                              const void* tm_raw,
                                              float* __restrict__ vn,
                                              float* __restrict__ tn,
                                              float* __restrict__ pn,
                                              float* __restrict__ an,
                                              short* __restrict__ Xp,
                                              short* __restrict__ Wp,
                                              float* __restrict__ swn_sq,
                                              int* __restrict__ labs,
                                              unsigned char* __restrict__ vmb,
                                              unsigned char* __restrict__ tmb) {
    __shared__ short tile[32][66];
    __shared__ float colsum[64];
    __shared__ float red[4];
    __shared__ float inv;
    int bx = blockIdx.x;
    int t = threadIdx.x;
    if (bx < 3072) {
        // ---- row L2-normalize ----
        const float* src;
        float* dst;
        short* Xpp = nullptr;
        int row, row_base = 0;
        if (bx < 256)       { src = vis;  dst = vn; Xpp = Xp; row = bx;        row_base = 0; }
        else if (bx < 512)  { src = text; dst = tn; Xpp = Xp; row = bx - 256;  row_base = BB; }
        else if (bx < 1792) { src = part; dst = pn; row = bx - 512; }
        else                { src = attr; dst = an; row = bx - 1792; }
        const float* s = src + (size_t)row * DD;
        float v0 = s[t];
        float v1 = s[t + 256];
        float v = waveSum(v0 * v0 + v1 * v1);
        if ((t & 63) == 0) red[t >> 6] = v;
        __syncthreads();
        if (t == 0) inv = 1.0f / sqrtf(red[0] + red[1] + red[2] + red[3]);
        __syncthreads();
        float a = v0 * inv, b = v1 * inv;
        float* d = dst + (size_t)row * DD;
        d[t] = a;
        d[t + 256] = b;
        if (Xpp) {
            int prow = row_base + row;
            int rt = prow >> 4, rl = prow & 15;
#pragma unroll
            for (int h = 0; h < 2; h++) {
                int c = t + h * 256;
                float val = h ? b : a;
                int kt = c >> 5;
                int lh = (c & 31) >> 3;
                int i = c & 7;
                int lane = (lh << 4) | rl;
                Xpp[((size_t)(rt * 16 + kt) * 64 + lane) * 8 + i] = to_bf16(val);
            }
        }
    } else if (bx < 5824) {
        // ---- W fragment-pack + fused column sq-norm ----
        int idx = bx - 3072;               // orig grid (172, 16)
        int bxw = idx % 172, byw = idx / 172;
        int c0 = bxw * 64, k0 = byw * 32;
        if (t < 64) colsum[t] = 0.f;
        __syncthreads();
        int cl64 = t & 63, kl = t >> 6;
        float ss = 0.f;
#pragma unroll
        for (int it = 0; it < 8; it++) {
            int k = k0 + kl + it * 4;
            int c = c0 + cl64;
            float w = (c < NCLS) ? W[(size_t)k * NCLS + c] : 0.f;
            ss = fmaf(w, w, ss);
            tile[kl + it * 4][cl64] = to_bf16(w);
        }
        atomicAdd(&colsum[cl64], ss);
        __syncthreads();
        int ctl = t >> 6, lane = t & 63;
        int cl = lane & 15, lh = lane >> 4;
        bf16x8 v;
#pragma unroll
        for (int i = 0; i < 8; i++) v[i] = tile[lh * 8 + i][ctl * 16 + cl];
        int ct = bxw * 4 + ctl;
        *(bf16x8*)(Wp + ((size_t)(ct * 16 + byw) * 64 + lane) * 8) = v;
        if (t < 64) atomicAdd(&swn_sq[c0 + t], colsum[t]);
    } else {
        // ---- dtype detect/convert ----
        __shared__ int is64, v32, t32;
        if (t == 0) {
            const int* L = (const int*)labels_raw;
            int f = 1;
            for (int j = 0; j < 16; j++) if (L[2 * j + 1] != 0) f = 0;
            is64 = f;
            const int* V = (const int*)vm_raw;
            f = 1;
            for (int j = 0; j < 16; j++) if ((unsigned)V[j] > 1u) f = 0;
            v32 = f;
            const int* T = (const int*)tm_raw;
            f = 1;
            for (int j = 0; j < 16; j++) if ((unsigned)T[j] > 1u) f = 0;
            t32 = f;
        }
        __syncthreads();
        if (t < BB) {
            if (is64) labs[t] = (int)((const long long*)labels_raw)[t];
            else      labs[t] = ((const int*)labels_raw)[t];
        }
        for (int j = t; j < BB * PP; j += 256) {
            vmb[j] = v32 ? (unsigned char)(((const int*)vm_raw)[j] != 0)
                         : (unsigned char)(((const unsigned char*)vm_raw)[j] != 0);
            tmb[j] = t32 ? (unsigned char)(((const int*)tm_raw)[j] != 0)
                         : (unsigned char)(((const unsigned char*)tm_raw)[j] != 0);
        }
    }
}

// =================== LAYER B: heavy (logits-MFMA + mask-loss + sims), deps on prep only ===================
// blocks [0,1376): logits MFMA + sumexp;  [1376,6496): mask loss;  [6496,6880): sim matrices
__global__ __launch_bounds__(256) void heavy_k(const short* __restrict__ Xp,
                                               const short* __restrict__ Wp,
                                               const float* __restrict__ swn_sq,
                                               float* __restrict__ sumexp,
                                               const float* __restrict__ seg,
                                               const int* __restrict__ masks,
                                               double* __restrict__ macc,
                                               const float* __restrict__ vn,
                                               const float* __restrict__ tn,
                                               const float* __restrict__ pn,
                                               const float* __restrict__ an,
                                               float* __restrict__ sims) {
    __shared__ float Xs[32][33], Ys[32][33];
    __shared__ float red[4];
    int bx = blockIdx.x;
    int t = threadIdx.x;
    if (bx < 1376) {
        // ---- logits MFMA ---- (orig grid (172, 8))
        int ctg = bx % 172, rtg = bx / 172;
        int wave = t >> 6, lane = t & 63;
        int l15 = lane & 15, lh = lane >> 4;
        int rt = rtg * 4 + wave;
        int ct0 = ctg * 4;
        f32x4 acc0 = {0.f, 0.f, 0.f, 0.f};
        f32x4 acc1 = acc0, acc2 = acc0, acc3 = acc0;
        const short* ap = Xp + (size_t)rt * 16 * 64 * 8 + lane * 8;
        const short* bp = Wp + (size_t)ct0 * 16 * 64 * 8 + lane * 8;
#pragma unroll
        for (int kt = 0; kt < 16; kt++) {
            bf16x8 a  = *(const bf16x8*)(ap + (size_t)kt * 512);
            bf16x8 b0 = *(const bf16x8*)(bp + (size_t)kt * 512);
            bf16x8 b1 = *(const bf16x8*)(bp + (size_t)(16 * 512) + kt * 512);
            bf16x8 b2 = *(const bf16x8*)(bp + (size_t)(32 * 512) + kt * 512);
            bf16x8 b3 = *(const bf16x8*)(bp + (size_t)(48 * 512) + kt * 512);
            acc0 = __builtin_amdgcn_mfma_f32_16x16x32_bf16(a, b0, acc0, 0, 0, 0);
            acc1 = __builtin_amdgcn_mfma_f32_16x16x32_bf16(a, b1, acc1, 0, 0, 0);
            acc2 = __builtin_amdgcn_mfma_f32_16x16x32_bf16(a, b2, acc2, 0, 0, 0);
            acc3 = __builtin_amdgcn_mfma_f32_16x16x32_bf16(a, b3, acc3, 0, 0, 0);
        }
        float s0 = 0.f, s1 = 0.f, s2 = 0.f, s3 = 0.f;
#pragma unroll
        for (int j = 0; j < 4; j++) {
            int c = (ct0 + j) * 16 + l15;
            bool valid = c < NCLS;
            float sc = valid ? SCALEF / sqrtf(swn_sq[c]) : 0.f;
            f32x4 accj = (j == 0) ? acc0 : (j == 1) ? acc1 : (j == 2) ? acc2 : acc3;
            s0 += valid ? __expf(accj[0] * sc) : 0.f;
            s1 += valid ? __expf(accj[1] * sc) : 0.f;
            s2 += valid ? __expf(accj[2] * sc) : 0.f;
            s3 += valid ? __expf(accj[3] * sc) : 0.f;
        }
#pragma unroll
        for (int o = 1; o < 16; o <<= 1) {
            s0 += __shfl_xor(s0, o);
            s1 += __shfl_xor(s1, o);
            s2 += __shfl_xor(s2, o);
            s3 += __shfl_xor(s3, o);
        }
        if (l15 == 0) {
            int rbase = rt * 16 + 4 * lh;
            atomicAdd(&sumexp[rbase + 0], s0);
            atomicAdd(&sumexp[rbase + 1], s1);
            atomicAdd(&sumexp[rbase + 2], s2);
            atomicAdd(&sumexp[rbase + 3], s3);
        }
    } else if (bx < 6496) {
        // ---- mask loss (4 px/thread) ----
        int tid = (bx - 1376) * 256 + t;
        int n = tid >> 10;
        int q = (tid & 1023) << 2;
        const float* p = seg + (size_t)n * (SEGC * 4096) + q;
        float4 x0 = *(const float4*)(p);
        float4 x1 = *(const float4*)(p + 4096);
        float4 x2 = *(const float4*)(p + 8192);
        float4 x3 = *(const float4*)(p + 12288);
        float4 x4 = *(const float4*)(p + 16384);
        float4 x5 = *(const float4*)(p + 20480);
        int4 mm = *(const int4*)(masks + (size_t)n * 4096 + q);
        float tot = 0.f;
#pragma unroll
        for (int j = 0; j < 4; j++) {
            float a0 = ((const float*)&x0)[j];
            float a1 = ((const float*)&x1)[j];
            float a2 = ((const float*)&x2)[j];
            float a3 = ((const float*)&x3)[j];
            float a4 = ((const float*)&x4)[j];
            float a5 = ((const float*)&x5)[j];
            int m = ((const int*)&mm)[j];
            float mx = fmaxf(fmaxf(fmaxf(a0, a1), fmaxf(a2, a3)), fmaxf(a4, a5));
            float se = __expf(a0 - mx) + __expf(a1 - mx) + __expf(a2 - mx) +
                       __expf(a3 - mx) + __expf(a4 - mx) + __expf(a5 - mx);
            float xm = (m == 0) ? a0 : (m == 1) ? a1 : (m == 2) ? a2
                     : (m == 3) ? a3 : (m == 4) ? a4 : a5;
            tot += logf(se) + mx - xm;
        }
        float v = waveSum(tot);
        if ((t & 63) == 0) red[t >> 6] = v;
        __syncthreads();
        if (t == 0)
            atomicAdd(&macc[bx & 63], (double)(red[0] + red[1] + red[2] + red[3]));
    } else {
        // ---- sim matrices ---- (orig grid (8,8,6))
        int idx2 = bx - 6496;
        int z = idx2 >> 6;
        int rem = idx2 & 63;
        int col0 = (rem & 7) * 32, row0 = (rem >> 3) * 32;
        const float* X;
        const float* Y;
        if (z == 0) { X = vn; Y = tn; }
        else { X = pn + (size_t)(z - 1) * BB * DD; Y = an + (size_t)(z - 1) * BB * DD; }
        float* C = sims + (size_t)z * BB * BB;
        int tx = t & 15, ty = t >> 4;
        float a00 = 0, a01 = 0, a10 = 0, a11 = 0;
        for (int kc = 0; kc < DD; kc += 32) {
#pragma unroll
            for (int l = 0; l < 4; l++) {
                int idx = t + l * 256;
                int r = idx >> 5, kk = idx & 31;
                Xs[r][kk] = X[(size_t)(row0 + r) * DD + kc + kk];
                Ys[r][kk] = Y[(size_t)(col0 + r) * DD + kc + kk];
            }
            __syncthreads();
#pragma unroll
            for (int kk = 0; kk < 32; kk++) {
                float x0 = Xs[ty * 2][kk], x1 = Xs[ty * 2 + 1][kk];
                float y0 = Ys[tx * 2][kk], y1 = Ys[tx * 2 + 1][kk];
                a00 = fmaf(x0, y0, a00);
                a01 = fmaf(x0, y1, a01);
                a10 = fmaf(x1, y0, a10);
                a11 = fmaf(x1, y1, a11);
            }
            __syncthreads();
        }
        int r = row0 + ty * 2, c = col0 + tx * 2;
        C[(size_t)r * BB + c] = a00;
        C[(size_t)r * BB + c + 1] = a01;
        C[(size_t)(r + 1) * BB + c] = a10;
        C[(size_t)(r + 1) * BB + c + 1] = a11;
    }
}

// =================== LAYER C: mid (boost + inst_label), deps on heavy ===================
// blocks [0,5): boost per part;  [5,261): per-sample label logit + instance loss
__global__ __launch_bounds__(256) void mid_k(const float* __restrict__ sims,
                                             unsigned char* __restrict__ b1,
                                             unsigned char* __restrict__ b2,
                                             const float* __restrict__ Xn,
                                             const float* __restrict__ W,
                                             const float* __restrict__ swn_sq,
                                             const float* __restrict__ sumexp,
                                             const int* __restrict__ labs,
                                             double* __restrict__ iacc) {
    __shared__ float rowv[BB], colv[BB];
    int bx = blockIdx.x;
    int t = threadIdx.x;
    if (bx < PP) {
        int i = bx;
        const float* S = sims + (size_t)(i + 1) * BB * BB;
        int c = t;
        rowv[c] = S[(size_t)i * BB + c];
        colv[c] = S[(size_t)c * BB + i];
        __syncthreads();
        float rv = rowv[c], cv = colv[c];
        int rank1 = 0, rank2 = 0;
        for (int j = 0; j < BB; j++) {
            rank1 += rowv[j] > rv;
            rank2 += colv[j] > cv;
        }
        unsigned char bo1 = 0, bo2 = 0;
        if (rank1 < 8) {
            int cnt = 0;
            for (int a = 0; a < BB; a++) cnt += S[(size_t)a * BB + c] > rv;
            bo1 = (cnt < 8);
        }
        if (rank2 < 8) {
            int cnt = 0;
            for (int b = 0; b < BB; b++) cnt += S[(size_t)c * BB + b] > cv;
            bo2 = (cnt < 8);
        }
        b1[i * BB + c] = bo1;
        b2[i * BB + c] = bo2;
    } else {
        int i = bx - PP;
        int lab = labs[i];
        float dv = 0.f, dt_ = 0.f;
        for (int k = t; k < DD; k += 256) {
            float w = W[(size_t)k * NCLS + lab];
            dv = fmaf(Xn[(size_t)i * DD + k], w, dv);
            dt_ = fmaf(Xn[(size_t)(BB + i) * DD + k], w, dt_);
        }
        float a = waveSum(dv), b = waveSum(dt_);
        if ((t & 63) == 0) { rowv[t >> 6] = a; colv[t >> 6] = b; }
        __syncthreads();
        if (t == 0) {
            float sc = SCALEF / sqrtf(swn_sq[lab]);
            float dvs = (rowv[0] + rowv[1] + rowv[2] + rowv[3]) * sc;
            float dts = (colv[0] + colv[1] + colv[2] + colv[3]) * sc;
            float li = (logf(sumexp[i]) - dvs) + (logf(sumexp[BB + i]) - dts);
            atomicAdd(iacc, (double)li);
        }
    }
}

// =================== local align (i<PP) + global align (i==PP) ===================
__global__ __launch_bounds__(256) void lalign_k(const float* __restrict__ sims,
                                                const int* __restrict__ labs,
                                                const unsigned char* __restrict__ vmb,
                                                const unsigned char* __restrict__ tmb,
                                                const unsigned char* __restrict__ b1,
                                                const unsigned char* __restrict__ b2,
                                                double* __restrict__ accL,
                                                double* __restrict__ accG) {
    int i = blockIdx.y, r = blockIdx.x, c = threadIdx.x;
    float v = 0.f;
    if (i == PP) {
        float s = sims[(size_t)r * BB + c];
        float x = (labs[r] == labs[c]) ? (-SPF * (s - ALPHAF)) : (SNF * (s - BETAF));
        v = softplusf(x);
    } else {
        const float* S = sims + (size_t)(i + 1) * BB * BB;
        float s = S[(size_t)r * BB + c];
        bool m = labs[r] == labs[c];
        float Lp = softplusf(-SPF * (s - ALPHAF));
        float Ln = softplusf(SNF * (s - BETAF));
        bool pmr = vmb[r * PP + i] != 0;
        bool pmc = vmb[c * PP + i] != 0;
        bool amc = tmb[c * PP + i] != 0;
        if (pmr && amc) v += (m || (b1[i * BB + c] != 0)) ? Lp : Ln;
        if (pmc && amc && pmr) v += (m || (b2[i * BB + r] != 0)) ? Lp : Ln;
    }
    __shared__ float red[4];
    v = waveSum(v);
    if ((threadIdx.x & 63) == 0) red[threadIdx.x >> 6] = v;
    __syncthreads();
    if (threadIdx.x == 0) {
        double* dst = (i == PP) ? &accG[r & 7] : &accL[r & 7];
        atomicAdd(dst, (double)(red[0] + red[1] + red[2] + red[3]));
    }
}

// =================== finalize ===================
// accs: [0..63] mask, [64..71] global, [72..79] local, [80] instance
__global__ void finalize_k(const double* __restrict__ accs, float* __restrict__ out) {
    int t = threadIdx.x;  // 64 threads
    double mv = accs[t];
    double gv = (t < 8) ? accs[64 + t] : 0.0;
    double lv = (t < 8) ? accs[72 + t] : 0.0;
#pragma unroll
    for (int o = 32; o; o >>= 1) {
        mv += __shfl_down(mv, o);
        gv += __shfl_down(gv, o);
        lv += __shfl_down(lv, o);
    }
    if (t == 0) {
        out[0] = (float)(accs[80] / (double)BB);
        out[1] = (float)((double)PP * mv / 5242880.0);
        out[2] = (float)(2.0 * gv / (double)BB);
        out[3] = (float)(lv / (double)(BB * PP));
    }
}

extern "C" void kernel_launch(void* const* d_in, const int* in_sizes, int n_in,
                              void* d_out, int out_size, void* d_ws, size_t ws_size,
                              hipStream_t stream) {
    const float* visual  = (const float*)d_in[0];
    const float* textual = (const float*)d_in[1];
    const float* part    = (const float*)d_in[2];
    const float* attr    = (const float*)d_in[3];
    const float* seg     = (const float*)d_in[4];
    const float* W       = (const float*)d_in[5];
    const void*  labels  = d_in[6];
    const int*   masks   = (const int*)d_in[7];
    const void*  vmask   = d_in[8];
    const void*  tmask   = d_in[9];
    float* out = (float*)d_out;

    float* ws = (float*)d_ws;
    short* Wp   = (short*)ws;                          // NCP*512 bf16
    float* base = ws + (size_t)NCP * DD / 2;
    short* Xp   = (short*)base;                        // 512*512 bf16 (= BB*DD floats)
    float* vn   = base + (size_t)BB * DD;
    float* tn   = vn + (size_t)BB * DD;
    float* pn   = tn + (size_t)BB * DD;
    float* an   = pn + (size_t)PP * BB * DD;
    float* swn_sq = an + (size_t)PP * BB * DD;         // NCP
    float* sims = swn_sq + NCP;                        // 6*65536
    float* sumexp = sims + 6 * BB * BB;                // 512
    int* labs = (int*)(sumexp + 2 * BB);               // 256
    unsigned char* vmb = (unsigned char*)(labs + BB);  // 1280
    unsigned char* tmb = vmb + BB * PP;
    unsigned char* b1  = tmb + BB * PP;
    unsigned char* b2  = b1 + BB * PP;
    uintptr_t aaddr = ((uintptr_t)(b2 + BB * PP) + 15) & ~(uintptr_t)15;
    double* accs = (double*)aaddr;                     // 81 doubles

    hipMemsetAsync(sumexp, 0, 2 * BB * sizeof(float), stream);
    hipMemsetAsync(swn_sq, 0, NCP * sizeof(float), stream);
    hipMemsetAsync(accs, 0, 81 * sizeof(double), stream);

    prep_k<<<5825, 256, 0, stream>>>(visual, textual, part, attr, W,
                                     labels, vmask, tmask,
                                     vn, tn, pn, an, Xp, Wp, swn_sq, labs, vmb, tmb);

    heavy_k<<<6880, 256, 0, stream>>>(Xp, Wp, swn_sq, sumexp,
                                      seg, masks, accs,
                                      vn, tn, pn, an, sims);

    mid_k<<<261, 256, 0, stream>>>(sims, b1, b2, vn, W, swn_sq, sumexp, labs, accs + 80);

    dim3 lg(BB, PP + 1);
    lalign_k<<<lg, 256, 0, stream>>>(sims, labs, vmb, tmb, b1, b2, accs + 72, accs + 64);

    finalize_k<<<1, 64, 0, stream>>>(accs, out);
}